// Round 1
// baseline (390.803 us; speedup 1.0000x reference)
//
#include <hip/hip_runtime.h>
#include <hip/hip_bf16.h>
#include <math.h>

typedef __attribute__((ext_vector_type(4))) float f32x4;
typedef __attribute__((ext_vector_type(8))) short short8_t;

constexpr int Bn = 4, Hn = 16, Sn = 2048, Dn = 64;
constexpr int QTILE = 64;   // rows per workgroup (4 waves x 16)
constexpr int KTILE = 32;   // keys per iteration

__device__ __forceinline__ unsigned short f2bf(float f) {
    union { float f; unsigned u; } x; x.f = f;
    unsigned r = x.u + 0x7fffu + ((x.u >> 16) & 1u);  // RTNE
    return (unsigned short)(r >> 16);
}

__global__ __launch_bounds__(256) void sdpa_fwd(
    const float* __restrict__ Qp, const float* __restrict__ Kp,
    const float* __restrict__ Vp, const void* __restrict__ Mp,
    float* __restrict__ Op)
{
    __shared__ unsigned short lds_k[KTILE * Dn];     // [key][d] bf16, XOR-swizzled
    __shared__ unsigned short lds_vt[Dn * KTILE];    // [v][k]   bf16, XOR-swizzled
    __shared__ unsigned short lds_p[4][16 * KTILE];  // per-wave P tile

    const int t = threadIdx.x;
    const int wave = t >> 6;
    const int lane = t & 63;
    const int g = lane >> 4;
    const int c = lane & 15;
    const int q0 = blockIdx.x * QTILE;
    const int bh = blockIdx.y;
    const int b = bh >> 4;

    // ---- mask dtype sniff: int32 (bytes 1..3 of each word zero) vs uint8 ----
    unsigned acc = 0;
    {
        const unsigned* mw = (const unsigned*)Mp;
#pragma unroll
        for (int i = 0; i < 32; ++i) acc |= (mw[i] & 0xFFFFFF00u);
    }
    const bool m_i32 = (acc == 0u);
    const int* mi32 = (const int*)Mp;
    const unsigned char* mu8 = (const unsigned char*)Mp;

    // ---- Q fragments (A-operand): row = c, k = h2*32 + g*8 + j; pre-scaled by 1/8
    short8_t qf[2];
    {
        const float* qsrc = Qp + ((size_t)bh * Sn + q0 + wave * 16 + c) * Dn + g * 8;
#pragma unroll
        for (int h2 = 0; h2 < 2; ++h2) {
            f32x4 f0 = *(const f32x4*)(qsrc + h2 * 32);
            f32x4 f1 = *(const f32x4*)(qsrc + h2 * 32 + 4);
            short8_t v;
            v[0] = (short)f2bf(f0[0] * 0.125f);
            v[1] = (short)f2bf(f0[1] * 0.125f);
            v[2] = (short)f2bf(f0[2] * 0.125f);
            v[3] = (short)f2bf(f0[3] * 0.125f);
            v[4] = (short)f2bf(f1[0] * 0.125f);
            v[5] = (short)f2bf(f1[1] * 0.125f);
            v[6] = (short)f2bf(f1[2] * 0.125f);
            v[7] = (short)f2bf(f1[3] * 0.125f);
            qf[h2] = v;
        }
    }

    f32x4 o[4];
#pragma unroll
    for (int i = 0; i < 4; ++i) o[i] = (f32x4){0.f, 0.f, 0.f, 0.f};
    float m_run[4] = {-INFINITY, -INFINITY, -INFINITY, -INFINITY};
    float l_run[4] = {0.f, 0.f, 0.f, 0.f};

    const size_t mbase = (size_t)b * Sn * Sn + (size_t)(q0 + wave * 16 + g * 4) * Sn + c;
    const size_t kvbase = (size_t)bh * Sn;

    for (int kt = 0; kt < Sn / KTILE; ++kt) {
        const int k0 = kt * KTILE;

        // ---- stage K tile -> lds_k (bf16, swizzle byte^=((key&7)<<4)) ----
        {
            const int key = t >> 3;
            const int d0 = (t & 7) * 8;
            const float* src = Kp + (kvbase + k0 + key) * Dn + d0;
            f32x4 f0 = *(const f32x4*)src;
            f32x4 f1 = *(const f32x4*)(src + 4);
            short8_t hv;
            hv[0] = (short)f2bf(f0[0]); hv[1] = (short)f2bf(f0[1]);
            hv[2] = (short)f2bf(f0[2]); hv[3] = (short)f2bf(f0[3]);
            hv[4] = (short)f2bf(f1[0]); hv[5] = (short)f2bf(f1[1]);
            hv[6] = (short)f2bf(f1[2]); hv[7] = (short)f2bf(f1[3]);
            *(short8_t*)&lds_k[key * 64 + (d0 ^ ((key & 7) << 3))] = hv;
        }
        // ---- stage V^T tile -> lds_vt (bf16 pairs, swizzled) ----
        {
            const int vv = t & 63;
            const int kq = (t >> 6) * 8;
#pragma unroll
            for (int sub = 0; sub < 4; ++sub) {
                const int kk = kq + sub * 2;
                float a0 = Vp[(kvbase + k0 + kk) * Dn + vv];
                float a1 = Vp[(kvbase + k0 + kk + 1) * Dn + vv];
                unsigned pk = (unsigned)f2bf(a0) | ((unsigned)f2bf(a1) << 16);
                *(unsigned*)&lds_vt[vv * 32 + (kk ^ ((vv & 3) << 3))] = pk;
            }
        }
        __syncthreads();

        // ---- QK^T: S[16q x 32k] per wave ----
        short8_t kfr[2][2];
#pragma unroll
        for (int e = 0; e < 2; ++e)
#pragma unroll
            for (int h2 = 0; h2 < 2; ++h2) {
                const int ke = e * 16 + c;
                const int d0 = h2 * 32 + g * 8;
                kfr[e][h2] = *(const short8_t*)&lds_k[ke * 64 + (d0 ^ ((ke & 7) << 3))];
            }
        f32x4 s0 = {0.f, 0.f, 0.f, 0.f}, s1 = {0.f, 0.f, 0.f, 0.f};
        s0 = __builtin_amdgcn_mfma_f32_16x16x32_bf16(qf[0], kfr[0][0], s0, 0, 0, 0);
        s0 = __builtin_amdgcn_mfma_f32_16x16x32_bf16(qf[1], kfr[0][1], s0, 0, 0, 0);
        s1 = __builtin_amdgcn_mfma_f32_16x16x32_bf16(qf[0], kfr[1][0], s1, 0, 0, 0);
        s1 = __builtin_amdgcn_mfma_f32_16x16x32_bf16(qf[1], kfr[1][1], s1, 0, 0, 0);

        // ---- mask + online softmax (rows g*4+r live in lanes g*16+c, reg r) ----
        float p0[4], p1[4], mx[4];
#pragma unroll
        for (int r = 0; r < 4; ++r) {
            float v0 = s0[r], v1 = s1[r];
            const size_t mi = mbase + (size_t)r * Sn + k0;
            int mm0, mm1;
            if (m_i32) { mm0 = mi32[mi]; mm1 = mi32[mi + 16]; }
            else       { mm0 = mu8[mi];  mm1 = mu8[mi + 16]; }
            if (mm0 != 0) v0 = -1e9f;
            if (mm1 != 0) v1 = -1e9f;
            p0[r] = v0; p1[r] = v1;
            mx[r] = fmaxf(v0, v1);
        }
#pragma unroll
        for (int sh = 1; sh < 16; sh <<= 1) {
#pragma unroll
            for (int r = 0; r < 4; ++r) mx[r] = fmaxf(mx[r], __shfl_xor(mx[r], sh));
        }
        float corr[4], rs[4];
#pragma unroll
        for (int r = 0; r < 4; ++r) {
            const float mn = fmaxf(m_run[r], mx[r]);
            corr[r] = __expf(m_run[r] - mn);
            m_run[r] = mn;
            p0[r] = __expf(p0[r] - mn);
            p1[r] = __expf(p1[r] - mn);
            rs[r] = p0[r] + p1[r];
        }
#pragma unroll
        for (int sh = 1; sh < 16; sh <<= 1) {
#pragma unroll
            for (int r = 0; r < 4; ++r) rs[r] += __shfl_xor(rs[r], sh);
        }
#pragma unroll
        for (int r = 0; r < 4; ++r) l_run[r] = l_run[r] * corr[r] + rs[r];

        // ---- P -> wave-private LDS (transpose to A-frag layout) ----
        unsigned short* pw = lds_p[wave];
#pragma unroll
        for (int r = 0; r < 4; ++r) {
            const int row = g * 4 + r;                       // row&3 == r
            pw[row * 32 + (c ^ (r << 3))] = f2bf(p0[r]);
            pw[row * 32 + ((c + 16) ^ (r << 3))] = f2bf(p1[r]);
        }
        // rescale O by correction factor
#pragma unroll
        for (int cg = 0; cg < 4; ++cg)
#pragma unroll
            for (int r = 0; r < 4; ++r) o[cg][r] *= corr[r];

        // ---- PV: O[16q x 64v] += P[16q x 32k] * V[32k x 64v] ----
        const short8_t pf = *(const short8_t*)&pw[c * 32 + ((g * 8) ^ ((c & 3) << 3))];
#pragma unroll
        for (int cg = 0; cg < 4; ++cg) {
            const int vv = cg * 16 + c;
            const short8_t vf = *(const short8_t*)&lds_vt[vv * 32 + ((g * 8) ^ ((vv & 3) << 3))];
            o[cg] = __builtin_amdgcn_mfma_f32_16x16x32_bf16(pf, vf, o[cg], 0, 0, 0);
        }
        __syncthreads();
    }

    // ---- epilogue: normalize and store fp32 ----
#pragma unroll
    for (int r = 0; r < 4; ++r) {
        const float inv = 1.0f / l_run[r];
        float* orow = Op + ((size_t)bh * Sn + q0 + wave * 16 + g * 4 + r) * Dn + c;
#pragma unroll
        for (int cg = 0; cg < 4; ++cg) orow[cg * 16] = o[cg][r] * inv;
    }
}

extern "C" void kernel_launch(void* const* d_in, const int* in_sizes, int n_in,
                              void* d_out, int out_size, void* d_ws, size_t ws_size,
                              hipStream_t stream) {
    (void)in_sizes; (void)n_in; (void)d_ws; (void)ws_size; (void)out_size;
    const float* Q = (const float*)d_in[0];
    const float* K = (const float*)d_in[1];
    const float* V = (const float*)d_in[2];
    const void*  M = d_in[3];
    float* O = (float*)d_out;
    dim3 grid(Sn / QTILE, Bn * Hn);
    sdpa_fwd<<<grid, dim3(256), 0, stream>>>(Q, K, V, M, O);
}

// Round 2
// 360.060 us; speedup vs baseline: 1.0854x; 1.0854x over previous
//
#include <hip/hip_runtime.h>
#include <hip/hip_bf16.h>
#include <math.h>

typedef __attribute__((ext_vector_type(4))) float f32x4;
typedef __attribute__((ext_vector_type(8))) short short8_t;

constexpr int Bn = 4, Hn = 16, Sn = 2048, Dn = 64;
constexpr int QTILE = 128;             // rows per workgroup (8 waves x 16)
constexpr int KTILE = 64;              // keys per iteration (== 64 mask bits)
constexpr int NWAVE = QTILE / 16;      // 8
constexpr int NQB = Sn / QTILE;        // 16
constexpr int NKT = Sn / KTILE;        // 32
constexpr int MW = Sn / 64;            // mask u64 words per row = 32
constexpr int NBLK = NQB * Bn * Hn;    // 1024

#if __has_builtin(__builtin_amdgcn_exp2f)
#define EXP2(x) __builtin_amdgcn_exp2f(x)
#else
#define EXP2(x) exp2f(x)
#endif

__device__ __forceinline__ unsigned short f2bf(float f) {
    union { float f; unsigned u; } x; x.f = f;
    unsigned r = x.u + 0x7fffu + ((x.u >> 16) & 1u);  // RTNE
    return (unsigned short)(r >> 16);
}
__device__ __forceinline__ int sw8(int row) { return (row ^ (row >> 3)) & 7; }

// ---- pre-pass: pack bool mask (int32 or uint8, sniffed) into 1 bit/elem ----
__global__ __launch_bounds__(256) void pack_mask(const void* __restrict__ Mp,
                                                 unsigned long long* __restrict__ PM) {
    unsigned accv = 0;
    {
        const unsigned* mw = (const unsigned*)Mp;
#pragma unroll
        for (int i = 0; i < 32; ++i) accv |= (mw[i] & 0xFFFFFF00u);
    }
    const bool i32 = (accv == 0u);
    const int lane = threadIdx.x & 63;
    const int wid = (int)((blockIdx.x * blockDim.x + threadIdx.x) >> 6);
    const int nw = (int)((gridDim.x * blockDim.x) >> 6);
    const int NW = Bn * Sn * MW;  // 262144 words
    const int* mi32 = (const int*)Mp;
    const unsigned char* mu8 = (const unsigned char*)Mp;
    for (int w = wid; w < NW; w += nw) {
        int m = i32 ? mi32[(size_t)w * 64 + lane] : (int)mu8[(size_t)w * 64 + lane];
        unsigned long long bal = __ballot(m != 0);
        if (lane == 0) PM[w] = bal;
    }
}

__global__ __launch_bounds__(512, 4) void sdpa_fwd(
    const float* __restrict__ Qp, const float* __restrict__ Kp,
    const float* __restrict__ Vp, const void* __restrict__ Mp,
    const unsigned long long* __restrict__ PM, float* __restrict__ Op)
{
    __shared__ unsigned short lds_k[KTILE * 64];           // 8 KB  [key][d]
    __shared__ unsigned short lds_vt[64 * KTILE];          // 8 KB  [v][k]
    __shared__ unsigned short lds_p[NWAVE][16 * KTILE];    // 16 KB [q][k] per wave

    const int t = threadIdx.x;
    const int wave = t >> 6;
    const int lane = t & 63;
    const int g = lane >> 4;
    const int c = lane & 15;

    // XCD-aware remap: 128 consecutive linear blocks per XCD -> all 16
    // q-blocks of a head land on one XCD (K/V becomes L2-resident).
    const int gid = blockIdx.x;
    const int lin = (gid & 7) * (NBLK / 8) + (gid >> 3);
    const int bh = lin >> 4;   // NQB == 16
    const int qb = lin & 15;
    const int b = bh >> 4;
    const int q0 = qb * QTILE;

    // mask dtype sniff (only needed for the no-workspace fallback)
    bool m_i32 = true;
    if (!PM) {
        unsigned accv = 0;
        const unsigned* mw = (const unsigned*)Mp;
#pragma unroll
        for (int i = 0; i < 32; ++i) accv |= (mw[i] & 0xFFFFFF00u);
        m_i32 = (accv == 0u);
    }
    const int* mi32 = (const int*)Mp;
    const unsigned char* mu8 = (const unsigned char*)Mp;

    // Q fragment (A-operand): row=c, k=h2*32+g*8+j; scale folds 1/sqrt(64)*log2(e)
    short8_t qf[2];
    {
        const float qscale = 0.125f * 1.44269504088896340736f;
        const float* qsrc = Qp + ((size_t)bh * Sn + q0 + wave * 16 + c) * Dn + g * 8;
#pragma unroll
        for (int h2 = 0; h2 < 2; ++h2) {
            f32x4 f0 = *(const f32x4*)(qsrc + h2 * 32);
            f32x4 f1 = *(const f32x4*)(qsrc + h2 * 32 + 4);
            short8_t v;
            v[0] = (short)f2bf(f0[0] * qscale); v[1] = (short)f2bf(f0[1] * qscale);
            v[2] = (short)f2bf(f0[2] * qscale); v[3] = (short)f2bf(f0[3] * qscale);
            v[4] = (short)f2bf(f1[0] * qscale); v[5] = (short)f2bf(f1[1] * qscale);
            v[6] = (short)f2bf(f1[2] * qscale); v[7] = (short)f2bf(f1[3] * qscale);
            qf[h2] = v;
        }
    }

    f32x4 o[4];
#pragma unroll
    for (int i = 0; i < 4; ++i) o[i] = (f32x4){0.f, 0.f, 0.f, 0.f};
    float m_run[4] = {-INFINITY, -INFINITY, -INFINITY, -INFINITY};
    float l_run[4] = {0.f, 0.f, 0.f, 0.f};

    const float* kbase = Kp + (size_t)bh * Sn * Dn;
    const float* vbase = Vp + (size_t)bh * Sn * Dn;
    const size_t mrow0 = (size_t)b * Sn + q0 + wave * 16 + g * 4;  // q-row of r=0

    for (int kt = 0; kt < NKT; ++kt) {
        const int k0 = kt * KTILE;

        // ---- stage K tile (64 keys x 64 d) ----
        {
            const int key = t >> 3;
            const int d0 = (t & 7) * 8;
            const float* src = kbase + (size_t)(k0 + key) * Dn + d0;
            f32x4 f0 = *(const f32x4*)src;
            f32x4 f1 = *(const f32x4*)(src + 4);
            short8_t hv;
            hv[0] = (short)f2bf(f0[0]); hv[1] = (short)f2bf(f0[1]);
            hv[2] = (short)f2bf(f0[2]); hv[3] = (short)f2bf(f0[3]);
            hv[4] = (short)f2bf(f1[0]); hv[5] = (short)f2bf(f1[1]);
            hv[6] = (short)f2bf(f1[2]); hv[7] = (short)f2bf(f1[3]);
            *(short8_t*)&lds_k[key * 64 + (d0 ^ (sw8(key) << 3))] = hv;
        }
        // ---- stage V^T tile (64 v-rows x 64 k) ----
        {
            const int vv = t & 63;
            const int kq = (t >> 6) * 8;
            short8_t hv;
#pragma unroll
            for (int j = 0; j < 8; ++j)
                hv[j] = (short)f2bf(vbase[(size_t)(k0 + kq + j) * Dn + vv]);
            *(short8_t*)&lds_vt[vv * 64 + (kq ^ (sw8(vv) << 3))] = hv;
        }
        __syncthreads();

        // ---- QK^T: S[16q x 64k] per wave ----
        f32x4 s[4];
#pragma unroll
        for (int e = 0; e < 4; ++e) s[e] = (f32x4){0.f, 0.f, 0.f, 0.f};
        __builtin_amdgcn_s_setprio(1);
#pragma unroll
        for (int e = 0; e < 4; ++e) {
            const int ke = e * 16 + c;
            const int swk = sw8(ke) << 3;
            short8_t kf0 = *(const short8_t*)&lds_k[ke * 64 + ((g * 8) ^ swk)];
            short8_t kf1 = *(const short8_t*)&lds_k[ke * 64 + ((32 + g * 8) ^ swk)];
            s[e] = __builtin_amdgcn_mfma_f32_16x16x32_bf16(qf[0], kf0, s[e], 0, 0, 0);
            s[e] = __builtin_amdgcn_mfma_f32_16x16x32_bf16(qf[1], kf1, s[e], 0, 0, 0);
        }
        __builtin_amdgcn_s_setprio(0);

        // ---- mask bits: one u64 per q-row covers this whole tile ----
        unsigned long long bits[4];
        if (PM) {
#pragma unroll
            for (int r = 0; r < 4; ++r)
                bits[r] = PM[(mrow0 + r) * MW + kt];
        } else {
#pragma unroll
            for (int r = 0; r < 4; ++r) {
                const size_t mi = (mrow0 + r) * Sn + k0 + c;
                unsigned long long bb = 0;
#pragma unroll
                for (int e = 0; e < 4; ++e) {
                    int mm = m_i32 ? mi32[mi + 16 * e] : (int)mu8[mi + 16 * e];
                    bb |= (unsigned long long)(mm != 0) << (c + 16 * e);
                }
                bits[r] = bb;
            }
        }

        // ---- masked online softmax (log2 domain) ----
        float p[4][4], mx[4];
#pragma unroll
        for (int r = 0; r < 4; ++r) {
            const unsigned lo = (unsigned)bits[r];
            const unsigned hi = (unsigned)(bits[r] >> 32);
            const unsigned t0 = lo >> c;
            const unsigned t1 = hi >> c;
            float v0 = (t0 & 1u)       ? -1e9f : s[0][r];
            float v1 = (t0 & 0x10000u) ? -1e9f : s[1][r];
            float v2 = (t1 & 1u)       ? -1e9f : s[2][r];
            float v3 = (t1 & 0x10000u) ? -1e9f : s[3][r];
            p[0][r] = v0; p[1][r] = v1; p[2][r] = v2; p[3][r] = v3;
            mx[r] = fmaxf(fmaxf(v0, v1), fmaxf(v2, v3));
        }
#pragma unroll
        for (int sh = 1; sh < 16; sh <<= 1) {
#pragma unroll
            for (int r = 0; r < 4; ++r) mx[r] = fmaxf(mx[r], __shfl_xor(mx[r], sh));
        }
        // defer-max: skip the O/l rescale unless the max grew past threshold
        float need = mx[0] - m_run[0];
        need = fmaxf(need, mx[1] - m_run[1]);
        need = fmaxf(need, mx[2] - m_run[2]);
        need = fmaxf(need, mx[3] - m_run[3]);
        if (!__all(need <= 8.0f)) {
#pragma unroll
            for (int r = 0; r < 4; ++r) {
                const float mn = fmaxf(m_run[r], mx[r]);
                const float corr = EXP2(m_run[r] - mn);
                m_run[r] = mn;
                l_run[r] *= corr;
#pragma unroll
                for (int cg = 0; cg < 4; ++cg) o[cg][r] *= corr;
            }
        }
        float rs[4];
#pragma unroll
        for (int r = 0; r < 4; ++r) {
            p[0][r] = EXP2(p[0][r] - m_run[r]);
            p[1][r] = EXP2(p[1][r] - m_run[r]);
            p[2][r] = EXP2(p[2][r] - m_run[r]);
            p[3][r] = EXP2(p[3][r] - m_run[r]);
            rs[r] = (p[0][r] + p[1][r]) + (p[2][r] + p[3][r]);
        }
#pragma unroll
        for (int sh = 1; sh < 16; sh <<= 1) {
#pragma unroll
            for (int r = 0; r < 4; ++r) rs[r] += __shfl_xor(rs[r], sh);
        }
#pragma unroll
        for (int r = 0; r < 4; ++r) l_run[r] += rs[r];

        // ---- P -> wave-private LDS (transpose to A-frag layout) ----
        unsigned short* pw = lds_p[wave];
#pragma unroll
        for (int r = 0; r < 4; ++r) {
            const int row = g * 4 + r;
            const int swp = sw8(row) << 3;
            pw[row * 64 + ((c)      ^ swp)] = f2bf(p[0][r]);
            pw[row * 64 + ((c + 16) ^ swp)] = f2bf(p[1][r]);
            pw[row * 64 + ((c + 32) ^ swp)] = f2bf(p[2][r]);
            pw[row * 64 + ((c + 48) ^ swp)] = f2bf(p[3][r]);
        }
        // ---- PV: O[16q x 64v] += P[16q x 64k] * V[64k x 64v] ----
        const int swc = sw8(c) << 3;
        const short8_t pf0 = *(const short8_t*)&pw[c * 64 + ((g * 8) ^ swc)];
        const short8_t pf1 = *(const short8_t*)&pw[c * 64 + ((32 + g * 8) ^ swc)];
        __builtin_amdgcn_s_setprio(1);
#pragma unroll
        for (int cg = 0; cg < 4; ++cg) {
            const int vv = cg * 16 + c;
            const int swv = sw8(vv) << 3;
            const short8_t vf0 = *(const short8_t*)&lds_vt[vv * 64 + ((g * 8) ^ swv)];
            const short8_t vf1 = *(const short8_t*)&lds_vt[vv * 64 + ((32 + g * 8) ^ swv)];
            o[cg] = __builtin_amdgcn_mfma_f32_16x16x32_bf16(pf0, vf0, o[cg], 0, 0, 0);
            o[cg] = __builtin_amdgcn_mfma_f32_16x16x32_bf16(pf1, vf1, o[cg], 0, 0, 0);
        }
        __builtin_amdgcn_s_setprio(0);
        __syncthreads();
    }

    // ---- epilogue: normalize and store fp32 ----
#pragma unroll
    for (int r = 0; r < 4; ++r) {
        const float inv = 1.0f / l_run[r];
        float* orow = Op + ((size_t)bh * Sn + q0 + wave * 16 + g * 4 + r) * Dn + c;
#pragma unroll
        for (int cg = 0; cg < 4; ++cg) orow[cg * 16] = o[cg][r] * inv;
    }
}

extern "C" void kernel_launch(void* const* d_in, const int* in_sizes, int n_in,
                              void* d_out, int out_size, void* d_ws, size_t ws_size,
                              hipStream_t stream) {
    (void)in_sizes; (void)n_in; (void)out_size;
    const float* Q = (const float*)d_in[0];
    const float* K = (const float*)d_in[1];
    const float* V = (const float*)d_in[2];
    const void*  M = d_in[3];
    float* O = (float*)d_out;

    unsigned long long* PM = nullptr;
    const size_t need = (size_t)Bn * Sn * Sn / 8;  // 2 MB packed mask
    if (ws_size >= need) {
        PM = (unsigned long long*)d_ws;
        pack_mask<<<256, 256, 0, stream>>>(M, PM);
    }
    sdpa_fwd<<<dim3(NBLK), dim3(512), 0, stream>>>(Q, K, V, M, PM, O);
}

// Round 4
// 238.783 us; speedup vs baseline: 1.6366x; 1.5079x over previous
//
#include <hip/hip_runtime.h>
#include <hip/hip_bf16.h>
#include <math.h>

typedef __attribute__((ext_vector_type(4)))  float f32x4;
typedef __attribute__((ext_vector_type(16))) float f32x16;
typedef __attribute__((ext_vector_type(8)))  short short8_t;
typedef __attribute__((ext_vector_type(4)))  short short4_t;

constexpr int Bn = 4, Hn = 16, Sn = 2048, Dn = 64;
constexpr int MW  = Sn / 64;   // packed-mask u64 words per row = 32
constexpr int NKT = Sn / 64;   // 64-key tiles = 32

__device__ __forceinline__ unsigned short f2bf(float f) {
    union { float f; unsigned u; } x; x.f = f;
    unsigned r = x.u + 0x7fffu + ((x.u >> 16) & 1u);  // RTNE
    return (unsigned short)(r >> 16);
}
__device__ __forceinline__ int sw8(int row) { return (row ^ (row >> 3)) & 7; }
__device__ __forceinline__ float exp2fast(float x) {
#if __has_builtin(__builtin_amdgcn_exp2f)
    return __builtin_amdgcn_exp2f(x);
#else
    float r; asm("v_exp_f32 %0, %1" : "=v"(r) : "v"(x)); return r;
#endif
}
__device__ __forceinline__ f32x16 zero16() {
    f32x16 z;
#pragma unroll
    for (int i = 0; i < 16; ++i) z[i] = 0.f;
    return z;
}
__device__ __forceinline__ unsigned cvtpk(float lo, float hi_) {
    __hip_bfloat162 h2 = __float22bfloat162_rn(make_float2(lo, hi_));
    union { __hip_bfloat162 h; unsigned u; } u; u.h = h2;
    return u.u;
}

// ================= prepass kernels =================
__global__ __launch_bounds__(256) void pack_mask(const void* __restrict__ Mp,
                                                 unsigned long long* __restrict__ PM) {
    unsigned accv = 0;
    {
        const unsigned* mw = (const unsigned*)Mp;
#pragma unroll
        for (int i = 0; i < 32; ++i) accv |= (mw[i] & 0xFFFFFF00u);
    }
    const bool i32 = (accv == 0u);
    const int lane = threadIdx.x & 63;
    const int wid = (int)((blockIdx.x * blockDim.x + threadIdx.x) >> 6);
    const int nw = (int)((gridDim.x * blockDim.x) >> 6);
    const int NW = Bn * Sn * MW;
    const int* mi32 = (const int*)Mp;
    const unsigned char* mu8 = (const unsigned char*)Mp;
    for (int w = wid; w < NW; w += nw) {
        int m = i32 ? mi32[(size_t)w * 64 + lane] : (int)mu8[(size_t)w * 64 + lane];
        unsigned long long bal = __ballot(m != 0);
        if (lane == 0) PM[w] = bal;
    }
}

__global__ __launch_bounds__(256) void convK(const float* __restrict__ K,
                                             unsigned short* __restrict__ Kb) {
    size_t i = ((size_t)blockIdx.x * 256 + threadIdx.x) * 8;
    f32x4 a = *(const f32x4*)(K + i);
    f32x4 b = *(const f32x4*)(K + i + 4);
    short8_t h;
    h[0]=(short)f2bf(a[0]); h[1]=(short)f2bf(a[1]); h[2]=(short)f2bf(a[2]); h[3]=(short)f2bf(a[3]);
    h[4]=(short)f2bf(b[0]); h[5]=(short)f2bf(b[1]); h[6]=(short)f2bf(b[2]); h[7]=(short)f2bf(b[3]);
    *(short8_t*)(Kb + i) = h;
}

__global__ __launch_bounds__(256) void convV(const float* __restrict__ V,
                                             unsigned short* __restrict__ Vt) {
    __shared__ unsigned short tile[64 * 72];
    const int bh = blockIdx.x, kt = blockIdx.y, t = threadIdx.x;
    const int k = t >> 2, vq = (t & 3) * 16;
    const float* src = V + ((size_t)bh * Sn + kt * 64 + k) * 64 + vq;
#pragma unroll
    for (int j = 0; j < 4; ++j) {
        f32x4 f = *(const f32x4*)(src + j * 4);
        short4_t h;
        h[0]=(short)f2bf(f[0]); h[1]=(short)f2bf(f[1]); h[2]=(short)f2bf(f[2]); h[3]=(short)f2bf(f[3]);
        *(short4_t*)&tile[k * 72 + vq + j * 4] = h;
    }
    __syncthreads();
#pragma unroll
    for (int j = 0; j < 2; ++j) {
        const int v = (t >> 3) + 32 * j;
        const int oct = t & 7;
        short8_t h;
#pragma unroll
        for (int i2 = 0; i2 < 8; ++i2) h[i2] = (short)tile[(oct * 8 + i2) * 72 + v];
        *(short8_t*)(Vt + ((size_t)bh * 64 + v) * Sn + kt * 64 + oct * 8) = h;
    }
}

// ================= main kernel (v3): swapped-QK^T 32x32 flash =================
__global__ __launch_bounds__(256) void sdpa_v3(
    const float* __restrict__ Qp, const unsigned short* __restrict__ Kb,
    const unsigned short* __restrict__ Vt, const unsigned long long* __restrict__ PM,
    float* __restrict__ Op)
{
    __shared__ __align__(16) char smem[32768];
    unsigned short* smK = (unsigned short*)smem;            // [2][4096]
    unsigned short* smV = (unsigned short*)(smem + 16384);  // [2][4096]
    unsigned short* smQ = (unsigned short*)smem;            // prologue overlay [128][72]

    const int t = threadIdx.x;
    const int w = t >> 6;
    const int l = t & 63;
    const int ql = l & 31;
    const int hi = l >> 5;

    // XCD-aware remap (1024 blocks = 8 XCD * 128)
    const int gid = blockIdx.x;
    const int lin = (gid & 7) * 128 + (gid >> 3);
    const int bh = lin >> 4;
    const int qb = lin & 15;
    const int b = bh >> 4;
    const int q0 = qb * 128;

    const unsigned short* KbB = Kb + (size_t)bh * Sn * 64;
    const unsigned short* VtB = Vt + (size_t)bh * 64 * Sn;

    // ---- prologue: cooperative Q load -> smQ (bf16, scaled), then frags ----
    {
        const float qscale = 0.125f * 1.44269504088896340736f;  // 1/sqrt(64) * log2(e)
        const float* Qbase = Qp + ((size_t)bh * Sn + q0) * Dn;
#pragma unroll
        for (int j = 0; j < 8; ++j) {
            const int flat = j * 256 + t;           // 2048 f32x4 chunks
            const int row = flat >> 4, c4 = (flat & 15) * 4;
            f32x4 f = *(const f32x4*)(Qbase + (size_t)flat * 4);
            short4_t h;
            h[0]=(short)f2bf(f[0]*qscale); h[1]=(short)f2bf(f[1]*qscale);
            h[2]=(short)f2bf(f[2]*qscale); h[3]=(short)f2bf(f[3]*qscale);
            *(short4_t*)&smQ[row * 72 + c4] = h;
        }
    }
    __syncthreads();
    short8_t qf[4];
    {
        const int rowl = w * 32 + ql;
#pragma unroll
        for (int tt = 0; tt < 4; ++tt)
            qf[tt] = *(const short8_t*)&smQ[rowl * 72 + tt * 16 + hi * 8];
    }
    __syncthreads();

    // ---- staging: global_load_lds 16B, linear LDS dest, inverse-swizzled src ----
    auto stage = [&](int kt, int buf) {
        const int row = t >> 3, oct = t & 7;
        const int row2 = row + 32;
        {
            const unsigned short* g = KbB + ((size_t)(kt * 64 + row)) * 64 + (oct ^ sw8(row)) * 8;
            __builtin_amdgcn_global_load_lds((const __attribute__((address_space(1))) unsigned int*)g,
                (__attribute__((address_space(3))) unsigned int*)(smK + buf * 4096 + t * 8), 16, 0, 0);
            const unsigned short* g2 = KbB + ((size_t)(kt * 64 + row2)) * 64 + (oct ^ sw8(row2)) * 8;
            __builtin_amdgcn_global_load_lds((const __attribute__((address_space(1))) unsigned int*)g2,
                (__attribute__((address_space(3))) unsigned int*)(smK + buf * 4096 + 2048 + t * 8), 16, 0, 0);
        }
        {
            const unsigned short* g = VtB + (size_t)row * Sn + kt * 64 + (oct ^ sw8(row)) * 8;
            __builtin_amdgcn_global_load_lds((const __attribute__((address_space(1))) unsigned int*)g,
                (__attribute__((address_space(3))) unsigned int*)(smV + buf * 4096 + t * 8), 16, 0, 0);
            const unsigned short* g2 = VtB + (size_t)row2 * Sn + kt * 64 + (oct ^ sw8(row2)) * 8;
            __builtin_amdgcn_global_load_lds((const __attribute__((address_space(1))) unsigned int*)g2,
                (__attribute__((address_space(3))) unsigned int*)(smV + buf * 4096 + 2048 + t * 8), 16, 0, 0);
        }
    };
    auto ldf = [&](const unsigned short* base, int row, int olog) -> short8_t {
        return *(const short8_t*)(base + row * 64 + (olog ^ sw8(row)) * 8);
    };

    f32x16 o0 = zero16(), o1 = zero16();
    float m_run = -INFINITY, l_run = 0.f;
    const int qrow = q0 + w * 32 + ql;
    const unsigned long long* pmrow = PM + ((size_t)b * Sn + qrow) * MW;

    stage(0, 0);
    __syncthreads();

    for (int kt = 0; kt < NKT; ++kt) {
        const int cur = kt & 1;
        if (kt + 1 < NKT) stage(kt + 1, cur ^ 1);
        const unsigned long long bits = pmrow[kt];
        const unsigned short* bK = smK + cur * 4096;
        const unsigned short* bV = smV + cur * 4096;

        // ---- QK^T (swapped): S^T[k][q], lane q = ql, keys in regs ----
        f32x16 s0 = zero16(), s1 = zero16();
        __builtin_amdgcn_s_setprio(1);
#pragma unroll
        for (int tt = 0; tt < 4; ++tt) {
            short8_t a0 = ldf(bK, ql,      2 * tt + hi);
            short8_t a1 = ldf(bK, 32 + ql, 2 * tt + hi);
            s0 = __builtin_amdgcn_mfma_f32_32x32x16_bf16(a0, qf[tt], s0, 0, 0, 0);
            s1 = __builtin_amdgcn_mfma_f32_32x32x16_bf16(a1, qf[tt], s1, 0, 0, 0);
        }
        __builtin_amdgcn_s_setprio(0);

        // ---- mask (reg r holds key = (r&3) + 8*(r>>2) + 4*hi [+32 for s1]) ----
        const unsigned long long bb = bits >> (hi * 4);
        const unsigned blo = (unsigned)bb, bhi = (unsigned)(bb >> 32);
#pragma unroll
        for (int r = 0; r < 16; ++r) {
            const int bp = 8 * (r >> 2) + (r & 3);
            s0[r] = ((blo >> bp) & 1u) ? -1e9f : s0[r];
            s1[r] = ((bhi >> bp) & 1u) ? -1e9f : s1[r];
        }

        // ---- online softmax, lane-local q-row ----
        float mx = fmaxf(s0[0], s1[0]);
#pragma unroll
        for (int r = 1; r < 16; ++r) mx = fmaxf(mx, fmaxf(s0[r], s1[r]));
        mx = fmaxf(mx, __shfl_xor(mx, 32));

        if (!__all(mx - m_run <= 8.0f)) {   // defer-max (THR=8, log2 domain)
            const float mn = fmaxf(m_run, mx);
            const float corr = exp2fast(m_run - mn);
            m_run = mn;
            l_run *= corr;
#pragma unroll
            for (int r = 0; r < 16; ++r) {
                const int qloc = (r & 3) + 8 * (r >> 2) + 4 * hi;
                const float cr = __shfl(corr, qloc);   // lane qloc holds q-row qloc's corr
                o0[r] *= cr; o1[r] *= cr;
            }
        }
        float rs = 0.f;
#pragma unroll
        for (int r = 0; r < 16; ++r) {
            s0[r] = exp2fast(s0[r] - m_run); rs += s0[r];
            s1[r] = exp2fast(s1[r] - m_run); rs += s1[r];
        }
        rs += __shfl_xor(rs, 32);
        l_run += rs;

        // ---- P -> bf16 packed quads ----
        unsigned pk0[8], pk1[8];
#pragma unroll
        for (int m = 0; m < 4; ++m) {
            pk0[2*m]   = cvtpk(s0[4*m],   s0[4*m+1]);
            pk0[2*m+1] = cvtpk(s0[4*m+2], s0[4*m+3]);
            pk1[2*m]   = cvtpk(s1[4*m],   s1[4*m+1]);
            pk1[2*m+1] = cvtpk(s1[4*m+2], s1[4*m+3]);
        }

        // ---- PV: build A-frag per k-step via half-wave exchange, 2 MFMAs each ----
        __builtin_amdgcn_s_setprio(1);
#pragma unroll
        for (int ks = 0; ks < 4; ++ks) {
            const int tt = ks & 1;
            const unsigned* pk = (ks < 2) ? pk0 : pk1;
            const unsigned a0 = pk[4*tt], a1 = pk[4*tt + 1];        // quad m=2tt
            const unsigned b0 = pk[4*tt + 2], b1 = pk[4*tt + 3];    // quad m=2tt+1
            const unsigned send0 = hi ? a0 : b0, send1 = hi ? a1 : b1;
            const unsigned self0 = hi ? b0 : a0, self1 = hi ? b1 : a1;
            const unsigned r0 = (unsigned)__shfl_xor((int)send0, 32);
            const unsigned r1 = (unsigned)__shfl_xor((int)send1, 32);
            union { unsigned u[4]; short8_t v; } pa;
            pa.u[0] = hi ? r0 : self0; pa.u[1] = hi ? r1 : self1;
            pa.u[2] = hi ? self0 : r0; pa.u[3] = hi ? self1 : r1;
            short8_t vf0 = ldf(bV, ql,      2 * ks + hi);
            short8_t vf1 = ldf(bV, 32 + ql, 2 * ks + hi);
            o0 = __builtin_amdgcn_mfma_f32_32x32x16_bf16(pa.v, vf0, o0, 0, 0, 0);
            o1 = __builtin_amdgcn_mfma_f32_32x32x16_bf16(pa.v, vf1, o1, 0, 0, 0);
        }
        __builtin_amdgcn_s_setprio(0);
        __syncthreads();   // drains gload_lds (next tile) + guards buffer reuse
    }

    // ---- epilogue: 1/l redistribution via shfl, store fp32 ----
    const float inv = 1.0f / l_run;
#pragma unroll
    for (int r = 0; r < 16; ++r) {
        const int qloc = (r & 3) + 8 * (r >> 2) + 4 * hi;
        const float iv = __shfl(inv, qloc);
        float* orow = Op + ((size_t)bh * Sn + q0 + w * 32 + qloc) * 64;
        orow[ql] = o0[r] * iv;
        orow[32 + ql] = o1[r] * iv;
    }
}

// ================= fallback (round-2 kernel, proven) =================
__global__ __launch_bounds__(512, 4) void sdpa_v2(
    const float* __restrict__ Qp, const float* __restrict__ Kp,
    const float* __restrict__ Vp, const void* __restrict__ Mp,
    const unsigned long long* __restrict__ PM, float* __restrict__ Op)
{
    __shared__ unsigned short lds_k[64 * 64];
    __shared__ unsigned short lds_vt[64 * 64];
    __shared__ unsigned short lds_p[8][16 * 64];

    const int t = threadIdx.x;
    const int wave = t >> 6;
    const int lane = t & 63;
    const int g = lane >> 4;
    const int c = lane & 15;

    const int gid = blockIdx.x;
    const int lin = (gid & 7) * 128 + (gid >> 3);
    const int bh = lin >> 4;
    const int qb = lin & 15;
    const int b = bh >> 4;
    const int q0 = qb * 128;

    bool m_i32 = true;
    if (!PM) {
        unsigned accv = 0;
        const unsigned* mw = (const unsigned*)Mp;
#pragma unroll
        for (int i = 0; i < 32; ++i) accv |= (mw[i] & 0xFFFFFF00u);
        m_i32 = (accv == 0u);
    }
    const int* mi32 = (const int*)Mp;
    const unsigned char* mu8 = (const unsigned char*)Mp;

    short8_t qf[2];
    {
        const float qscale = 0.125f * 1.44269504088896340736f;
        const float* qsrc = Qp + ((size_t)bh * Sn + q0 + wave * 16 + c) * Dn + g * 8;
#pragma unroll
        for (int h2 = 0; h2 < 2; ++h2) {
            f32x4 f0 = *(const f32x4*)(qsrc + h2 * 32);
            f32x4 f1 = *(const f32x4*)(qsrc + h2 * 32 + 4);
            short8_t v;
            v[0]=(short)f2bf(f0[0]*qscale); v[1]=(short)f2bf(f0[1]*qscale);
            v[2]=(short)f2bf(f0[2]*qscale); v[3]=(short)f2bf(f0[3]*qscale);
            v[4]=(short)f2bf(f1[0]*qscale); v[5]=(short)f2bf(f1[1]*qscale);
            v[6]=(short)f2bf(f1[2]*qscale); v[7]=(short)f2bf(f1[3]*qscale);
            qf[h2] = v;
        }
    }

    f32x4 o[4];
#pragma unroll
    for (int i = 0; i < 4; ++i) o[i] = (f32x4){0.f, 0.f, 0.f, 0.f};
    float m_run[4] = {-INFINITY, -INFINITY, -INFINITY, -INFINITY};
    float l_run[4] = {0.f, 0.f, 0.f, 0.f};

    const float* kbase = Kp + (size_t)bh * Sn * Dn;
    const float* vbase = Vp + (size_t)bh * Sn * Dn;
    const size_t mrow0 = (size_t)b * Sn + q0 + wave * 16 + g * 4;

    for (int kt = 0; kt < NKT; ++kt) {
        const int k0 = kt * 64;
        {
            const int key = t >> 3;
            const int d0 = (t & 7) * 8;
            const float* src = kbase + (size_t)(k0 + key) * Dn + d0;
            f32x4 f0 = *(const f32x4*)src;
            f32x4 f1 = *(const f32x4*)(src + 4);
            short8_t hv;
            hv[0]=(short)f2bf(f0[0]); hv[1]=(short)f2bf(f0[1]);
            hv[2]=(short)f2bf(f0[2]); hv[3]=(short)f2bf(f0[3]);
            hv[4]=(short)f2bf(f1[0]); hv[5]=(short)f2bf(f1[1]);
            hv[6]=(short)f2bf(f1[2]); hv[7]=(short)f2bf(f1[3]);
            *(short8_t*)&lds_k[key * 64 + (d0 ^ (sw8(key) << 3))] = hv;
        }
        {
            const int vv = t & 63;
            const int kq = (t >> 6) * 8;
            short8_t hv;
#pragma unroll
            for (int j = 0; j < 8; ++j)
                hv[j] = (short)f2bf(vbase[(size_t)(k0 + kq + j) * Dn + vv]);
            *(short8_t*)&lds_vt[vv * 64 + (kq ^ (sw8(vv) << 3))] = hv;
        }
        __syncthreads();

        f32x4 s[4];
#pragma unroll
        for (int e = 0; e < 4; ++e) s[e] = (f32x4){0.f, 0.f, 0.f, 0.f};
        __builtin_amdgcn_s_setprio(1);
#pragma unroll
        for (int e = 0; e < 4; ++e) {
            const int ke = e * 16 + c;
            const int swk = sw8(ke) << 3;
            short8_t kf0 = *(const short8_t*)&lds_k[ke * 64 + ((g * 8) ^ swk)];
            short8_t kf1 = *(const short8_t*)&lds_k[ke * 64 + ((32 + g * 8) ^ swk)];
            s[e] = __builtin_amdgcn_mfma_f32_16x16x32_bf16(qf[0], kf0, s[e], 0, 0, 0);
            s[e] = __builtin_amdgcn_mfma_f32_16x16x32_bf16(qf[1], kf1, s[e], 0, 0, 0);
        }
        __builtin_amdgcn_s_setprio(0);

        unsigned long long bits[4];
        if (PM) {
#pragma unroll
            for (int r = 0; r < 4; ++r) bits[r] = PM[(mrow0 + r) * MW + kt];
        } else {
#pragma unroll
            for (int r = 0; r < 4; ++r) {
                const size_t mi = (mrow0 + r) * Sn + k0 + c;
                unsigned long long bbv = 0;
#pragma unroll
                for (int e = 0; e < 4; ++e) {
                    int mm = m_i32 ? mi32[mi + 16 * e] : (int)mu8[mi + 16 * e];
                    bbv |= (unsigned long long)(mm != 0) << (c + 16 * e);
                }
                bits[r] = bbv;
            }
        }

        float p[4][4], mx[4];
#pragma unroll
        for (int r = 0; r < 4; ++r) {
            const unsigned lo = (unsigned)bits[r];
            const unsigned hh = (unsigned)(bits[r] >> 32);
            const unsigned t0 = lo >> c;
            const unsigned t1 = hh >> c;
            float v0 = (t0 & 1u)       ? -1e9f : s[0][r];
            float v1 = (t0 & 0x10000u) ? -1e9f : s[1][r];
            float v2 = (t1 & 1u)       ? -1e9f : s[2][r];
            float v3 = (t1 & 0x10000u) ? -1e9f : s[3][r];
            p[0][r] = v0; p[1][r] = v1; p[2][r] = v2; p[3][r] = v3;
            mx[r] = fmaxf(fmaxf(v0, v1), fmaxf(v2, v3));
        }
#pragma unroll
        for (int sh = 1; sh < 16; sh <<= 1) {
#pragma unroll
            for (int r = 0; r < 4; ++r) mx[r] = fmaxf(mx[r], __shfl_xor(mx[r], sh));
        }
        float need = mx[0] - m_run[0];
        need = fmaxf(need, mx[1] - m_run[1]);
        need = fmaxf(need, mx[2] - m_run[2]);
        need = fmaxf(need, mx[3] - m_run[3]);
        if (!__all(need <= 8.0f)) {
#pragma unroll
            for (int r = 0; r < 4; ++r) {
                const float mn = fmaxf(m_run[r], mx[r]);
                const float corr = exp2fast(m_run[r] - mn);
                m_run[r] = mn;
                l_run[r] *= corr;
#pragma unroll
                for (int cg = 0; cg < 4; ++cg) o[cg][r] *= corr;
            }
        }
        float rsv[4];
#pragma unroll
        for (int r = 0; r < 4; ++r) {
            p[0][r] = exp2fast(p[0][r] - m_run[r]);
            p[1][r] = exp2fast(p[1][r] - m_run[r]);
            p[2][r] = exp2fast(p[2][r] - m_run[r]);
            p[3][r] = exp2fast(p[3][r] - m_run[r]);
            rsv[r] = (p[0][r] + p[1][r]) + (p[2][r] + p[3][r]);
        }
#pragma unroll
        for (int sh = 1; sh < 16; sh <<= 1) {
#pragma unroll
            for (int r = 0; r < 4; ++r) rsv[r] += __shfl_xor(rsv[r], sh);
        }
#pragma unroll
        for (int r = 0; r < 4; ++r) l_run[r] += rsv[r];

        unsigned short* pw = lds_p[wave];
#pragma unroll
        for (int r = 0; r < 4; ++r) {
            const int row = g * 4 + r;
            const int swp = sw8(row) << 3;
            pw[row * 64 + ((c)      ^ swp)] = f2bf(p[0][r]);
            pw[row * 64 + ((c + 16) ^ swp)] = f2bf(p[1][r]);
            pw[row * 64 + ((c + 32) ^ swp)] = f2bf(p[2][r]);
            pw[row * 64 + ((c + 48) ^ swp)] = f2bf(p[3][r]);
        }
        const int swc = sw8(c) << 3;
        const short8_t pf0 = *(const short8_t*)&pw[c * 64 + ((g * 8) ^ swc)];
        const short8_t pf1 = *(const short8_t*)&pw[c * 64 + ((32 + g * 8) ^ swc)];
        __builtin_amdgcn_s_setprio(1);
#pragma unroll
        for (int cg = 0; cg < 4; ++cg) {
            const int vv = cg * 16 + c;
            const int swv = sw8(vv) << 3;
            const short8_t vf0 = *(const short8_t*)&lds_vt[vv * 64 + ((g * 8) ^ swv)];
            const short8_t vf1 = *(const short8_t*)&lds_vt[vv * 64 + ((32 + g * 8) ^ swv)];
            o[cg] = __builtin_amdgcn_mfma_f32_16x16x32_bf16(pf0, vf0, o[cg], 0, 0, 0);
            o[cg] = __builtin_amdgcn_mfma_f32_16x16x32_bf16(pf1, vf1, o[cg], 0, 0, 0);
        }
        __builtin_amdgcn_s_setprio(0);
        __syncthreads();
    }

#pragma unroll
    for (int r = 0; r < 4; ++r) {
        const float inv = 1.0f / l_run[r];
        float* orow = Op + ((size_t)bh * Sn + q0 + wave * 16 + g * 4 + r) * Dn + c;
#pragma unroll
        for (int cg = 0; cg < 4; ++cg) orow[cg * 16] = o[cg][r] * inv;
    }
}

extern "C" void kernel_launch(void* const* d_in, const int* in_sizes, int n_in,
                              void* d_out, int out_size, void* d_ws, size_t ws_size,
                              hipStream_t stream) {
    (void)in_sizes; (void)n_in; (void)out_size;
    const float* Q = (const float*)d_in[0];
    const float* K = (const float*)d_in[1];
    const float* V = (const float*)d_in[2];
    const void*  M = d_in[3];
    float* O = (float*)d_out;

    const size_t pmB = (size_t)Bn * Sn * MW * 8;            // 2 MB packed mask
    const size_t kvB = (size_t)Bn * Hn * Sn * Dn * 2;       // 16.78 MB each

    if (ws_size >= pmB + 2 * kvB) {
        unsigned long long* PM = (unsigned long long*)d_ws;
        unsigned short* Kb = (unsigned short*)((char*)d_ws + pmB);
        unsigned short* Vt = (unsigned short*)((char*)d_ws + pmB + kvB);
        pack_mask<<<256, 256, 0, stream>>>(M, PM);
        convK<<<4096, 256, 0, stream>>>(K, Kb);
        convV<<<dim3(Bn * Hn, NKT), 256, 0, stream>>>(V, Vt);
        sdpa_v3<<<dim3(1024), dim3(256), 0, stream>>>(Q, Kb, Vt, PM, O);
    } else {
        unsigned long long* PM = nullptr;
        if (ws_size >= pmB) {
            PM = (unsigned long long*)d_ws;
            pack_mask<<<256, 256, 0, stream>>>(M, PM);
        }
        sdpa_v2<<<dim3(1024), dim3(512), 0, stream>>>(Q, K, V, M, PM, O);
    }
}

// Round 5
// 157.524 us; speedup vs baseline: 2.4809x; 1.5159x over previous
//
#include <hip/hip_runtime.h>
#include <hip/hip_bf16.h>
#include <math.h>

typedef __attribute__((ext_vector_type(4)))  float f32x4;
typedef __attribute__((ext_vector_type(16))) float f32x16;
typedef __attribute__((ext_vector_type(8)))  short short8_t;
typedef __attribute__((ext_vector_type(4)))  short short4_t;

constexpr int Bn = 4, Hn = 16, Sn = 2048, Dn = 64;
constexpr int MW  = Sn / 64;   // packed-mask u64 words per row = 32
constexpr int NKT = Sn / 64;   // 64-key tiles = 32

__device__ __forceinline__ unsigned short f2bf(float f) {
    union { float f; unsigned u; } x; x.f = f;
    unsigned r = x.u + 0x7fffu + ((x.u >> 16) & 1u);  // RTNE
    return (unsigned short)(r >> 16);
}
__device__ __forceinline__ int sw8(int row) { return (row ^ (row >> 3)) & 7; }
__device__ __forceinline__ float exp2fast(float x) {
#if __has_builtin(__builtin_amdgcn_exp2f)
    return __builtin_amdgcn_exp2f(x);
#else
    float r; asm("v_exp_f32 %0, %1" : "=v"(r) : "v"(x)); return r;
#endif
}
__device__ __forceinline__ float max3f(float a, float b, float c) {
    return fmaxf(fmaxf(a, b), c);   // fuses to v_max3_f32
}
__device__ __forceinline__ f32x16 zero16() {
    f32x16 z;
#pragma unroll
    for (int i = 0; i < 16; ++i) z[i] = 0.f;
    return z;
}
__device__ __forceinline__ unsigned cvtpk(float lo, float hi_) {
    __hip_bfloat162 h2 = __float22bfloat162_rn(make_float2(lo, hi_));
    union { __hip_bfloat162 h; unsigned u; } u; u.h = h2;
    return u.u;
}
// v_permlane32_swap_b32: X' = [X_lo, Y_lo], Y' = [X_hi, Y_hi]
__device__ __forceinline__ void pswap(unsigned &x, unsigned &y) {
    asm("v_permlane32_swap_b32 %0, %1" : "+v"(x), "+v"(y));
}

// ================= prepass kernels =================
__global__ __launch_bounds__(256) void pack_mask(const void* __restrict__ Mp,
                                                 unsigned long long* __restrict__ PM) {
    unsigned accv = 0;
    {
        const unsigned* mw = (const unsigned*)Mp;
#pragma unroll
        for (int i = 0; i < 8; ++i) accv |= (mw[i] & 0xFFFFFF00u);
    }
    const bool i32 = (accv == 0u);
    const int lane = threadIdx.x & 63;
    const int wv = (int)((blockIdx.x * 256 + threadIdx.x) >> 6);   // 4096 waves
    const int w0 = wv * (Bn * Sn * MW / 4096);                     // 64 words/wave
    const int* mi32 = (const int*)Mp;
    const unsigned char* mu8 = (const unsigned char*)Mp;
    for (int j = 0; j < 64; j += 4) {
        int m0, m1, m2, m3;
        if (i32) {
            m0 = mi32[(size_t)(w0 + j) * 64 + lane];
            m1 = mi32[(size_t)(w0 + j + 1) * 64 + lane];
            m2 = mi32[(size_t)(w0 + j + 2) * 64 + lane];
            m3 = mi32[(size_t)(w0 + j + 3) * 64 + lane];
        } else {
            m0 = mu8[(size_t)(w0 + j) * 64 + lane];
            m1 = mu8[(size_t)(w0 + j + 1) * 64 + lane];
            m2 = mu8[(size_t)(w0 + j + 2) * 64 + lane];
            m3 = mu8[(size_t)(w0 + j + 3) * 64 + lane];
        }
        unsigned long long b0 = __ballot(m0 != 0);
        unsigned long long b1 = __ballot(m1 != 0);
        unsigned long long b2 = __ballot(m2 != 0);
        unsigned long long b3 = __ballot(m3 != 0);
        if (lane == 0) {
            PM[w0 + j] = b0; PM[w0 + j + 1] = b1;
            PM[w0 + j + 2] = b2; PM[w0 + j + 3] = b3;
        }
    }
}

__global__ __launch_bounds__(256) void convK(const float* __restrict__ K,
                                             unsigned short* __restrict__ Kb) {
    size_t i = ((size_t)blockIdx.x * 256 + threadIdx.x) * 8;
    f32x4 a = *(const f32x4*)(K + i);
    f32x4 b = *(const f32x4*)(K + i + 4);
    short8_t h;
    h[0]=(short)f2bf(a[0]); h[1]=(short)f2bf(a[1]); h[2]=(short)f2bf(a[2]); h[3]=(short)f2bf(a[3]);
    h[4]=(short)f2bf(b[0]); h[5]=(short)f2bf(b[1]); h[6]=(short)f2bf(b[2]); h[7]=(short)f2bf(b[3]);
    *(short8_t*)(Kb + i) = h;
}

__global__ __launch_bounds__(256) void convV(const float* __restrict__ V,
                                             unsigned short* __restrict__ Vt) {
    __shared__ unsigned short tile[64 * 72];
    const int bh = blockIdx.x, kt = blockIdx.y, t = threadIdx.x;
    const int k = t >> 2, vq = (t & 3) * 16;
    const float* src = V + ((size_t)bh * Sn + kt * 64 + k) * 64 + vq;
#pragma unroll
    for (int j = 0; j < 4; ++j) {
        f32x4 f = *(const f32x4*)(src + j * 4);
        short4_t h;
        h[0]=(short)f2bf(f[0]); h[1]=(short)f2bf(f[1]); h[2]=(short)f2bf(f[2]); h[3]=(short)f2bf(f[3]);
        *(short4_t*)&tile[k * 72 + vq + j * 4] = h;
    }
    __syncthreads();
#pragma unroll
    for (int j = 0; j < 2; ++j) {
        const int v = (t >> 3) + 32 * j;
        const int oct = t & 7;
        short8_t h;
#pragma unroll
        for (int i2 = 0; i2 < 8; ++i2) h[i2] = (short)tile[(oct * 8 + i2) * 72 + v];
        *(short8_t*)(Vt + ((size_t)bh * 64 + v) * Sn + kt * 64 + oct * 8) = h;
    }
}

// ================= main kernel (v4): swapped-QK^T, permlane PV, MFMA-l =================
__global__ __launch_bounds__(256) void sdpa_v3(
    const float* __restrict__ Qp, const unsigned short* __restrict__ Kb,
    const unsigned short* __restrict__ Vt, const unsigned long long* __restrict__ PM,
    float* __restrict__ Op)
{
    __shared__ __align__(16) char smem[33280];
    unsigned short* smK = (unsigned short*)smem;            // [2][4096]
    unsigned short* smV = (unsigned short*)(smem + 16384);  // [2][4096]
    float* smL = (float*)(smem + 32768);                    // [4][32] row sums
    unsigned short* smQ = (unsigned short*)smem;            // prologue overlay [128][72]

    const int t = threadIdx.x;
    const int w = t >> 6;
    const int l = t & 63;
    const int ql = l & 31;
    const int hi = l >> 5;

    // XCD-aware remap (1024 blocks = 8 XCD * 128)
    const int gid = blockIdx.x;
    const int lin = (gid & 7) * 128 + (gid >> 3);
    const int bh = lin >> 4;
    const int qb = lin & 15;
    const int b = bh >> 4;
    const int q0 = qb * 128;

    const unsigned short* KbB = Kb + (size_t)bh * Sn * 64;
    const unsigned short* VtB = Vt + (size_t)bh * 64 * Sn;

    // ---- prologue: cooperative Q load -> smQ (bf16, scaled), then frags ----
    {
        const float qscale = 0.125f * 1.44269504088896340736f;  // 1/sqrt(64) * log2(e)
        const float* Qbase = Qp + ((size_t)bh * Sn + q0) * Dn;
#pragma unroll
        for (int j = 0; j < 8; ++j) {
            const int flat = j * 256 + t;           // 2048 f32x4 chunks
            const int row = flat >> 4, c4 = (flat & 15) * 4;
            f32x4 f = *(const f32x4*)(Qbase + (size_t)flat * 4);
            short4_t h;
            h[0]=(short)f2bf(f[0]*qscale); h[1]=(short)f2bf(f[1]*qscale);
            h[2]=(short)f2bf(f[2]*qscale); h[3]=(short)f2bf(f[3]*qscale);
            *(short4_t*)&smQ[row * 72 + c4] = h;
        }
    }
    __syncthreads();
    short8_t qf[4];
    {
        const int rowl = w * 32 + ql;
#pragma unroll
        for (int tt = 0; tt < 4; ++tt)
            qf[tt] = *(const short8_t*)&smQ[rowl * 72 + tt * 16 + hi * 8];
    }
    __syncthreads();

    // ones B-frag: B[k][0] = 1.0 -> column 0 of the l-MFMA
    union { unsigned u[4]; short8_t v; } onesf;
    {
        const unsigned ov = (ql == 0) ? 0x3F803F80u : 0u;
        onesf.u[0] = ov; onesf.u[1] = ov; onesf.u[2] = ov; onesf.u[3] = ov;
    }

    // ---- staging: global_load_lds 16B, linear LDS dest, inverse-swizzled src ----
    auto stage = [&](int kt, int buf) {
        const int row = t >> 3, oct = t & 7;
        const int row2 = row + 32;
        {
            const unsigned short* g = KbB + ((size_t)(kt * 64 + row)) * 64 + (oct ^ sw8(row)) * 8;
            __builtin_amdgcn_global_load_lds((const __attribute__((address_space(1))) unsigned int*)g,
                (__attribute__((address_space(3))) unsigned int*)(smK + buf * 4096 + t * 8), 16, 0, 0);
            const unsigned short* g2 = KbB + ((size_t)(kt * 64 + row2)) * 64 + (oct ^ sw8(row2)) * 8;
            __builtin_amdgcn_global_load_lds((const __attribute__((address_space(1))) unsigned int*)g2,
                (__attribute__((address_space(3))) unsigned int*)(smK + buf * 4096 + 2048 + t * 8), 16, 0, 0);
        }
        {
            const unsigned short* g = VtB + (size_t)row * Sn + kt * 64 + (oct ^ sw8(row)) * 8;
            __builtin_amdgcn_global_load_lds((const __attribute__((address_space(1))) unsigned int*)g,
                (__attribute__((address_space(3))) unsigned int*)(smV + buf * 4096 + t * 8), 16, 0, 0);
            const unsigned short* g2 = VtB + (size_t)row2 * Sn + kt * 64 + (oct ^ sw8(row2)) * 8;
            __builtin_amdgcn_global_load_lds((const __attribute__((address_space(1))) unsigned int*)g2,
                (__attribute__((address_space(3))) unsigned int*)(smV + buf * 4096 + 2048 + t * 8), 16, 0, 0);
        }
    };
    auto ldf = [&](const unsigned short* base, int row, int olog) -> short8_t {
        return *(const short8_t*)(base + row * 64 + (olog ^ sw8(row)) * 8);
    };

    f32x16 o0 = zero16(), o1 = zero16(), o2 = zero16();
    float m_run = -INFINITY;
    const int qrow = q0 + w * 32 + ql;
    const unsigned long long* pmrow = PM + ((size_t)b * Sn + qrow) * MW;

    stage(0, 0);
    __syncthreads();

    for (int kt = 0; kt < NKT; ++kt) {
        const int cur = kt & 1;
        if (kt + 1 < NKT) stage(kt + 1, cur ^ 1);
        const unsigned long long bits = pmrow[kt];
        const unsigned short* bK = smK + cur * 4096;
        const unsigned short* bV = smV + cur * 4096;

        // ---- QK^T (swapped): S^T[k][q], lane q = ql, keys in regs ----
        f32x16 s0 = zero16(), s1 = zero16();
        __builtin_amdgcn_s_setprio(1);
#pragma unroll
        for (int tt = 0; tt < 4; ++tt) {
            short8_t a0 = ldf(bK, ql,      2 * tt + hi);
            short8_t a1 = ldf(bK, 32 + ql, 2 * tt + hi);
            s0 = __builtin_amdgcn_mfma_f32_32x32x16_bf16(a0, qf[tt], s0, 0, 0, 0);
            s1 = __builtin_amdgcn_mfma_f32_32x32x16_bf16(a1, qf[tt], s1, 0, 0, 0);
        }
        __builtin_amdgcn_s_setprio(0);

        // ---- mask (reg r holds key = (r&3) + 8*(r>>2) + 4*hi [+32 for s1]) ----
        const unsigned long long bb = bits >> (hi * 4);
        const unsigned blo = (unsigned)bb, bhi = (unsigned)(bb >> 32);
#pragma unroll
        for (int r = 0; r < 16; ++r) {
            const int bp = 8 * (r >> 2) + (r & 3);
            s0[r] = ((blo >> bp) & 1u) ? -1e9f : s0[r];
            s1[r] = ((bhi >> bp) & 1u) ? -1e9f : s1[r];
        }

        // ---- online softmax max (v_max3 chains), lane-local q-row ----
        float mx0 = fmaxf(s0[0], s0[1]);
        float mx1 = fmaxf(s1[0], s1[1]);
#pragma unroll
        for (int r = 2; r < 16; r += 2) {
            mx0 = max3f(mx0, s0[r], s0[r + 1]);
            mx1 = max3f(mx1, s1[r], s1[r + 1]);
        }
        float mx = fmaxf(mx0, mx1);
        mx = fmaxf(mx, __shfl_xor(mx, 32));

        if (!__all(mx - m_run <= 8.0f)) {   // defer-max (THR=8, log2 domain)
            const float mn = fmaxf(m_run, mx);
            const float corr = exp2fast(m_run - mn);
            m_run = mn;
#pragma unroll
            for (int r = 0; r < 16; ++r) {
                const int qloc = (r & 3) + 8 * (r >> 2) + 4 * hi;
                const float cr = __shfl(corr, qloc);   // lane qloc holds q-row qloc's corr
                o0[r] *= cr; o1[r] *= cr; o2[r] *= cr;
            }
        }
#pragma unroll
        for (int r = 0; r < 16; ++r) {
            s0[r] = exp2fast(s0[r] - m_run);
            s1[r] = exp2fast(s1[r] - m_run);
        }

        // ---- P -> bf16 packed quads ----
        unsigned pk0[8], pk1[8];
#pragma unroll
        for (int m = 0; m < 4; ++m) {
            pk0[2*m]   = cvtpk(s0[4*m],   s0[4*m+1]);
            pk0[2*m+1] = cvtpk(s0[4*m+2], s0[4*m+3]);
            pk1[2*m]   = cvtpk(s1[4*m],   s1[4*m+1]);
            pk1[2*m+1] = cvtpk(s1[4*m+2], s1[4*m+3]);
        }

        // ---- PV + l: A-frags via permlane32_swap, 3 MFMAs per k-slice ----
        __builtin_amdgcn_s_setprio(1);
#pragma unroll
        for (int ks = 0; ks < 4; ++ks) {
            unsigned* pk = (ks < 2) ? pk0 : pk1;
            const int base = (ks & 1) * 4;
            unsigned x0 = pk[base],     y0 = pk[base + 2];
            unsigned x1 = pk[base + 1], y1 = pk[base + 3];
            pswap(x0, y0);   // x0' = frag word0, y0' = frag word2
            pswap(x1, y1);   // x1' = frag word1, y1' = frag word3
            union { unsigned u[4]; short8_t v; } pa;
            pa.u[0] = x0; pa.u[1] = x1; pa.u[2] = y0; pa.u[3] = y1;
            short8_t vf0 = ldf(bV, ql,      2 * ks + hi);
            short8_t vf1 = ldf(bV, 32 + ql, 2 * ks + hi);
            o0 = __builtin_amdgcn_mfma_f32_32x32x16_bf16(pa.v, vf0, o0, 0, 0, 0);
            o1 = __builtin_amdgcn_mfma_f32_32x32x16_bf16(pa.v, vf1, o1, 0, 0, 0);
            o2 = __builtin_amdgcn_mfma_f32_32x32x16_bf16(pa.v, onesf.v, o2, 0, 0, 0);
        }
        __builtin_amdgcn_s_setprio(0);
        __syncthreads();   // drains gload_lds (next tile) + guards buffer reuse
    }

    // ---- epilogue: redistribute l (col 0 of o2 lives in lanes ql==0) ----
    if (ql == 0) {
#pragma unroll
        for (int r = 0; r < 16; ++r)
            smL[w * 32 + (r & 3) + 8 * (r >> 2) + 4 * hi] = o2[r];
    }
    __syncthreads();
#pragma unroll
    for (int r = 0; r < 16; ++r) {
        const int qloc = (r & 3) + 8 * (r >> 2) + 4 * hi;
        const float iv = 1.0f / smL[w * 32 + qloc];   // broadcast LDS read
        float* orow = Op + ((size_t)bh * Sn + q0 + w * 32 + qloc) * 64;
        orow[ql] = o0[r] * iv;
        orow[32 + ql] = o1[r] * iv;
    }
}

// ================= fallback (round-2 kernel, proven) =================
__global__ __launch_bounds__(512, 4) void sdpa_v2(
    const float* __restrict__ Qp, const float* __restrict__ Kp,
    const float* __restrict__ Vp, const void* __restrict__ Mp,
    const unsigned long long* __restrict__ PM, float* __restrict__ Op)
{
    __shared__ unsigned short lds_k[64 * 64];
    __shared__ unsigned short lds_vt[64 * 64];
    __shared__ unsigned short lds_p[8][16 * 64];

    const int t = threadIdx.x;
    const int wave = t >> 6;
    const int lane = t & 63;
    const int g = lane >> 4;
    const int c = lane & 15;

    const int gid = blockIdx.x;
    const int lin = (gid & 7) * 128 + (gid >> 3);
    const int bh = lin >> 4;
    const int qb = lin & 15;
    const int b = bh >> 4;
    const int q0 = qb * 128;

    bool m_i32 = true;
    if (!PM) {
        unsigned accv = 0;
        const unsigned* mw = (const unsigned*)Mp;
#pragma unroll
        for (int i = 0; i < 32; ++i) accv |= (mw[i] & 0xFFFFFF00u);
        m_i32 = (accv == 0u);
    }
    const int* mi32 = (const int*)Mp;
    const unsigned char* mu8 = (const unsigned char*)Mp;

    short8_t qf[2];
    {
        const float qscale = 0.125f * 1.44269504088896340736f;
        const float* qsrc = Qp + ((size_t)bh * Sn + q0 + wave * 16 + c) * Dn + g * 8;
#pragma unroll
        for (int h2 = 0; h2 < 2; ++h2) {
            f32x4 f0 = *(const f32x4*)(qsrc + h2 * 32);
            f32x4 f1 = *(const f32x4*)(qsrc + h2 * 32 + 4);
            short8_t v;
            v[0]=(short)f2bf(f0[0]*qscale); v[1]=(short)f2bf(f0[1]*qscale);
            v[2]=(short)f2bf(f0[2]*qscale); v[3]=(short)f2bf(f0[3]*qscale);
            v[4]=(short)f2bf(f1[0]*qscale); v[5]=(short)f2bf(f1[1]*qscale);
            v[6]=(short)f2bf(f1[2]*qscale); v[7]=(short)f2bf(f1[3]*qscale);
            qf[h2] = v;
        }
    }

    f32x4 o[4];
#pragma unroll
    for (int i = 0; i < 4; ++i) o[i] = (f32x4){0.f, 0.f, 0.f, 0.f};
    float m_run[4] = {-INFINITY, -INFINITY, -INFINITY, -INFINITY};
    float l_run[4] = {0.f, 0.f, 0.f, 0.f};

    const float* kbase = Kp + (size_t)bh * Sn * Dn;
    const float* vbase = Vp + (size_t)bh * Sn * Dn;
    const size_t mrow0 = (size_t)b * Sn + q0 + wave * 16 + g * 4;

    for (int kt = 0; kt < NKT; ++kt) {
        const int k0 = kt * 64;
        {
            const int key = t >> 3;
            const int d0 = (t & 7) * 8;
            const float* src = kbase + (size_t)(k0 + key) * Dn + d0;
            f32x4 f0 = *(const f32x4*)src;
            f32x4 f1 = *(const f32x4*)(src + 4);
            short8_t hv;
            hv[0]=(short)f2bf(f0[0]); hv[1]=(short)f2bf(f0[1]);
            hv[2]=(short)f2bf(f0[2]); hv[3]=(short)f2bf(f0[3]);
            hv[4]=(short)f2bf(f1[0]); hv[5]=(short)f2bf(f1[1]);
            hv[6]=(short)f2bf(f1[2]); hv[7]=(short)f2bf(f1[3]);
            *(short8_t*)&lds_k[key * 64 + (d0 ^ (sw8(key) << 3))] = hv;
        }
        {
            const int vv = t & 63;
            const int kq = (t >> 6) * 8;
            short8_t hv;
#pragma unroll
            for (int j = 0; j < 8; ++j)
                hv[j] = (short)f2bf(vbase[(size_t)(k0 + kq + j) * Dn + vv]);
            *(short8_t*)&lds_vt[vv * 64 + (kq ^ (sw8(vv) << 3))] = hv;
        }
        __syncthreads();

        f32x4 s[4];
#pragma unroll
        for (int e = 0; e < 4; ++e) s[e] = (f32x4){0.f, 0.f, 0.f, 0.f};
        __builtin_amdgcn_s_setprio(1);
#pragma unroll
        for (int e = 0; e < 4; ++e) {
            const int ke = e * 16 + c;
            const int swk = sw8(ke) << 3;
            short8_t kf0 = *(const short8_t*)&lds_k[ke * 64 + ((g * 8) ^ swk)];
            short8_t kf1 = *(const short8_t*)&lds_k[ke * 64 + ((32 + g * 8) ^ swk)];
            s[e] = __builtin_amdgcn_mfma_f32_16x16x32_bf16(qf[0], kf0, s[e], 0, 0, 0);
            s[e] = __builtin_amdgcn_mfma_f32_16x16x32_bf16(qf[1], kf1, s[e], 0, 0, 0);
        }
        __builtin_amdgcn_s_setprio(0);

        unsigned long long bits[4];
        if (PM) {
#pragma unroll
            for (int r = 0; r < 4; ++r) bits[r] = PM[(mrow0 + r) * MW + kt];
        } else {
#pragma unroll
            for (int r = 0; r < 4; ++r) {
                const size_t mi = (mrow0 + r) * Sn + k0 + c;
                unsigned long long bbv = 0;
#pragma unroll
                for (int e = 0; e < 4; ++e) {
                    int mm = m_i32 ? mi32[mi + 16 * e] : (int)mu8[mi + 16 * e];
                    bbv |= (unsigned long long)(mm != 0) << (c + 16 * e);
                }
                bits[r] = bbv;
            }
        }

        float p[4][4], mx[4];
#pragma unroll
        for (int r = 0; r < 4; ++r) {
            const unsigned lo = (unsigned)bits[r];
            const unsigned hh = (unsigned)(bits[r] >> 32);
            const unsigned t0 = lo >> c;
            const unsigned t1 = hh >> c;
            float v0 = (t0 & 1u)       ? -1e9f : s[0][r];
            float v1 = (t0 & 0x10000u) ? -1e9f : s[1][r];
            float v2 = (t1 & 1u)       ? -1e9f : s[2][r];
            float v3 = (t1 & 0x10000u) ? -1e9f : s[3][r];
            p[0][r] = v0; p[1][r] = v1; p[2][r] = v2; p[3][r] = v3;
            mx[r] = fmaxf(fmaxf(v0, v1), fmaxf(v2, v3));
        }
#pragma unroll
        for (int sh = 1; sh < 16; sh <<= 1) {
#pragma unroll
            for (int r = 0; r < 4; ++r) mx[r] = fmaxf(mx[r], __shfl_xor(mx[r], sh));
        }
        float need = mx[0] - m_run[0];
        need = fmaxf(need, mx[1] - m_run[1]);
        need = fmaxf(need, mx[2] - m_run[2]);
        need = fmaxf(need, mx[3] - m_run[3]);
        if (!__all(need <= 8.0f)) {
#pragma unroll
            for (int r = 0; r < 4; ++r) {
                const float mn = fmaxf(m_run[r], mx[r]);
                const float corr = exp2fast(m_run[r] - mn);
                m_run[r] = mn;
                l_run[r] *= corr;
#pragma unroll
                for (int cg = 0; cg < 4; ++cg) o[cg][r] *= corr;
            }
        }
        float rsv[4];
#pragma unroll
        for (int r = 0; r < 4; ++r) {
            p[0][r] = exp2fast(p[0][r] - m_run[r]);
            p[1][r] = exp2fast(p[1][r] - m_run[r]);
            p[2][r] = exp2fast(p[2][r] - m_run[r]);
            p[3][r] = exp2fast(p[3][r] - m_run[r]);
            rsv[r] = (p[0][r] + p[1][r]) + (p[2][r] + p[3][r]);
        }
#pragma unroll
        for (int sh = 1; sh < 16; sh <<= 1) {
#pragma unroll
            for (int r = 0; r < 4; ++r) rsv[r] += __shfl_xor(rsv[r], sh);
        }
#pragma unroll
        for (int r = 0; r < 4; ++r) l_run[r] += rsv[r];

        unsigned short* pw = lds_p[wave];
#pragma unroll
        for (int r = 0; r < 4; ++r) {
            const int row = g * 4 + r;
            const int swp = sw8(row) << 3;
            pw[row * 64 + ((c)      ^ swp)] = f2bf(p[0][r]);
            pw[row * 64 + ((c + 16) ^ swp)] = f2bf(p[1][r]);
            pw[row * 64 + ((c + 32) ^ swp)] = f2bf(p[2][r]);
            pw[row * 64 + ((c + 48) ^ swp)] = f2bf(p[3][r]);
        }
        const int swc = sw8(c) << 3;
        const short8_t pf0 = *(const short8_t*)&pw[c * 64 + ((g * 8) ^ swc)];
        const short8_t pf1 = *(const short8_t*)&pw[c * 64 + ((32 + g * 8) ^ swc)];
        __builtin_amdgcn_s_setprio(1);
#pragma unroll
        for (int cg = 0; cg < 4; ++cg) {
            const int vv = cg * 16 + c;
            const int swv = sw8(vv) << 3;
            const short8_t vf0 = *(const short8_t*)&lds_vt[vv * 64 + ((g * 8) ^ swv)];
            const short8_t vf1 = *(const short8_t*)&lds_vt[vv * 64 + ((32 + g * 8) ^ swv)];
            o[cg] = __builtin_amdgcn_mfma_f32_16x16x32_bf16(pf0, vf0, o[cg], 0, 0, 0);
            o[cg] = __builtin_amdgcn_mfma_f32_16x16x32_bf16(pf1, vf1, o[cg], 0, 0, 0);
        }
        __builtin_amdgcn_s_setprio(0);
        __syncthreads();
    }

#pragma unroll
    for (int r = 0; r < 4; ++r) {
        const float inv = 1.0f / l_run[r];
        float* orow = Op + ((size_t)bh * Sn + q0 + wave * 16 + g * 4 + r) * Dn + c;
#pragma unroll
        for (int cg = 0; cg < 4; ++cg) orow[cg * 16] = o[cg][r] * inv;
    }
}

extern "C" void kernel_launch(void* const* d_in, const int* in_sizes, int n_in,
                              void* d_out, int out_size, void* d_ws, size_t ws_size,
                              hipStream_t stream) {
    (void)in_sizes; (void)n_in; (void)out_size;
    const float* Q = (const float*)d_in[0];
    const float* K = (const float*)d_in[1];
    const float* V = (const float*)d_in[2];
    const void*  M = d_in[3];
    float* O = (float*)d_out;

    const size_t pmB = (size_t)Bn * Sn * MW * 8;            // 2 MB packed mask
    const size_t kvB = (size_t)Bn * Hn * Sn * Dn * 2;       // 16.78 MB each

    if (ws_size >= pmB + 2 * kvB) {
        unsigned long long* PM = (unsigned long long*)d_ws;
        unsigned short* Kb = (unsigned short*)((char*)d_ws + pmB);
        unsigned short* Vt = (unsigned short*)((char*)d_ws + pmB + kvB);
        pack_mask<<<1024, 256, 0, stream>>>(M, PM);
        convK<<<4096, 256, 0, stream>>>(K, Kb);
        convV<<<dim3(Bn * Hn, NKT), 256, 0, stream>>>(V, Vt);
        sdpa_v3<<<dim3(1024), dim3(256), 0, stream>>>(Q, Kb, Vt, PM, O);
    } else {
        unsigned long long* PM = nullptr;
        if (ws_size >= pmB) {
            PM = (unsigned long long*)d_ws;
            pack_mask<<<1024, 256, 0, stream>>>(M, PM);
        }
        sdpa_v2<<<dim3(1024), dim3(512), 0, stream>>>(Q, K, V, M, PM, O);
    }
}

// Round 6
// 146.543 us; speedup vs baseline: 2.6668x; 1.0749x over previous
//
#include <hip/hip_runtime.h>
#include <hip/hip_bf16.h>
#include <math.h>

typedef __attribute__((ext_vector_type(4)))  float f32x4;
typedef __attribute__((ext_vector_type(16))) float f32x16;
typedef __attribute__((ext_vector_type(8)))  short short8_t;
typedef __attribute__((ext_vector_type(4)))  short short4_t;

constexpr int Bn = 4, Hn = 16, Sn = 2048, Dn = 64;
constexpr int MW  = Sn / 64;   // packed-mask u64 words per row = 32
constexpr int NKT = Sn / 64;   // 64-key tiles = 32

__device__ __forceinline__ unsigned short f2bf(float f) {
    union { float f; unsigned u; } x; x.f = f;
    unsigned r = x.u + 0x7fffu + ((x.u >> 16) & 1u);  // RTNE
    return (unsigned short)(r >> 16);
}
__device__ __forceinline__ int sw8(int row) { return (row ^ (row >> 3)) & 7; }
__device__ __forceinline__ float exp2fast(float x) {
#if __has_builtin(__builtin_amdgcn_exp2f)
    return __builtin_amdgcn_exp2f(x);
#else
    float r; asm("v_exp_f32 %0, %1" : "=v"(r) : "v"(x)); return r;
#endif
}
__device__ __forceinline__ float max3f(float a, float b, float c) {
    return fmaxf(fmaxf(a, b), c);   // fuses to v_max3_f32
}
__device__ __forceinline__ f32x16 zero16() {
    f32x16 z;
#pragma unroll
    for (int i = 0; i < 16; ++i) z[i] = 0.f;
    return z;
}
__device__ __forceinline__ unsigned cvtpk(float lo, float hi_) {
    __hip_bfloat162 h2 = __float22bfloat162_rn(make_float2(lo, hi_));
    union { __hip_bfloat162 h; unsigned u; } u; u.h = h2;
    return u.u;
}
// v_permlane32_swap_b32: X' = [X_lo, Y_lo], Y' = [X_hi, Y_hi]
__device__ __forceinline__ void pswap(unsigned &x, unsigned &y) {
    asm("v_permlane32_swap_b32 %0, %1" : "+v"(x), "+v"(y));
}

// ================= prepass kernels =================
__global__ __launch_bounds__(256) void pack_mask(const void* __restrict__ Mp,
                                                 unsigned long long* __restrict__ PM) {
    unsigned accv = 0;
    {
        const unsigned* mw = (const unsigned*)Mp;
#pragma unroll
        for (int i = 0; i < 8; ++i) accv |= (mw[i] & 0xFFFFFF00u);
    }
    const bool i32 = (accv == 0u);
    const int lane = threadIdx.x & 63;
    const int wv = (int)((blockIdx.x * 256 + threadIdx.x) >> 6);   // 4096 waves
    const int w0 = wv * (Bn * Sn * MW / 4096);                     // 64 words/wave
    const int* mi32 = (const int*)Mp;
    const unsigned char* mu8 = (const unsigned char*)Mp;
    for (int j = 0; j < 64; j += 4) {
        int m0, m1, m2, m3;
        if (i32) {
            m0 = mi32[(size_t)(w0 + j) * 64 + lane];
            m1 = mi32[(size_t)(w0 + j + 1) * 64 + lane];
            m2 = mi32[(size_t)(w0 + j + 2) * 64 + lane];
            m3 = mi32[(size_t)(w0 + j + 3) * 64 + lane];
        } else {
            m0 = mu8[(size_t)(w0 + j) * 64 + lane];
            m1 = mu8[(size_t)(w0 + j + 1) * 64 + lane];
            m2 = mu8[(size_t)(w0 + j + 2) * 64 + lane];
            m3 = mu8[(size_t)(w0 + j + 3) * 64 + lane];
        }
        unsigned long long b0 = __ballot(m0 != 0);
        unsigned long long b1 = __ballot(m1 != 0);
        unsigned long long b2 = __ballot(m2 != 0);
        unsigned long long b3 = __ballot(m3 != 0);
        if (lane == 0) {
            PM[w0 + j] = b0; PM[w0 + j + 1] = b1;
            PM[w0 + j + 2] = b2; PM[w0 + j + 3] = b3;
        }
    }
}

__global__ __launch_bounds__(256) void convK(const float* __restrict__ K,
                                             unsigned short* __restrict__ Kb) {
    size_t i = ((size_t)blockIdx.x * 256 + threadIdx.x) * 8;
    f32x4 a = *(const f32x4*)(K + i);
    f32x4 b = *(const f32x4*)(K + i + 4);
    short8_t h;
    h[0]=(short)f2bf(a[0]); h[1]=(short)f2bf(a[1]); h[2]=(short)f2bf(a[2]); h[3]=(short)f2bf(a[3]);
    h[4]=(short)f2bf(b[0]); h[5]=(short)f2bf(b[1]); h[6]=(short)f2bf(b[2]); h[7]=(short)f2bf(b[3]);
    *(short8_t*)(Kb + i) = h;
}

__global__ __launch_bounds__(256) void convV(const float* __restrict__ V,
                                             unsigned short* __restrict__ Vt) {
    __shared__ unsigned short tile[64 * 72];
    const int bh = blockIdx.x, kt = blockIdx.y, t = threadIdx.x;
    const int k = t >> 2, vq = (t & 3) * 16;
    const float* src = V + ((size_t)bh * Sn + kt * 64 + k) * 64 + vq;
#pragma unroll
    for (int j = 0; j < 4; ++j) {
        f32x4 f = *(const f32x4*)(src + j * 4);
        short4_t h;
        h[0]=(short)f2bf(f[0]); h[1]=(short)f2bf(f[1]); h[2]=(short)f2bf(f[2]); h[3]=(short)f2bf(f[3]);
        *(short4_t*)&tile[k * 72 + vq + j * 4] = h;
    }
    __syncthreads();
#pragma unroll
    for (int j = 0; j < 2; ++j) {
        const int v = (t >> 3) + 32 * j;
        const int oct = t & 7;
        short8_t h;
#pragma unroll
        for (int i2 = 0; i2 < 8; ++i2) h[i2] = (short)tile[(oct * 8 + i2) * 72 + v];
        *(short8_t*)(Vt + ((size_t)bh * 64 + v) * Sn + kt * 64 + oct * 8) = h;
    }
}

// ====== main kernel (v5): swapped-QK^T, permlane PV, register-slim for 3 waves/SIMD ======
__global__ __launch_bounds__(256, 3) void sdpa_v3(
    const float* __restrict__ Qp, const unsigned short* __restrict__ Kb,
    const unsigned short* __restrict__ Vt, const unsigned long long* __restrict__ PM,
    float* __restrict__ Op)
{
    __shared__ __align__(16) char smem[32768];
    unsigned short* smK = (unsigned short*)smem;            // [2][4096]
    unsigned short* smV = (unsigned short*)(smem + 16384);  // [2][4096]
    unsigned short* smQ = (unsigned short*)smem;            // prologue overlay [128][72]

    const int t = threadIdx.x;
    const int w = t >> 6;
    const int l = t & 63;
    const int ql = l & 31;
    const int hi = l >> 5;

    // XCD-aware remap (1024 blocks = 8 XCD * 128)
    const int gid = blockIdx.x;
    const int lin = (gid & 7) * 128 + (gid >> 3);
    const int bh = lin >> 4;
    const int qb = lin & 15;
    const int b = bh >> 4;
    const int q0 = qb * 128;

    const unsigned short* KbB = Kb + (size_t)bh * Sn * 64;
    const unsigned short* VtB = Vt + (size_t)bh * 64 * Sn;

    // ---- prologue: cooperative Q load -> smQ (bf16, scaled), then frags ----
    {
        const float qscale = 0.125f * 1.44269504088896340736f;  // 1/sqrt(64) * log2(e)
        const float* Qbase = Qp + ((size_t)bh * Sn + q0) * Dn;
#pragma unroll
        for (int j = 0; j < 8; ++j) {
            const int flat = j * 256 + t;           // 2048 f32x4 chunks
            const int row = flat >> 4, c4 = (flat & 15) * 4;
            f32x4 f = *(const f32x4*)(Qbase + (size_t)flat * 4);
            short4_t h;
            h[0]=(short)f2bf(f[0]*qscale); h[1]=(short)f2bf(f[1]*qscale);
            h[2]=(short)f2bf(f[2]*qscale); h[3]=(short)f2bf(f[3]*qscale);
            *(short4_t*)&smQ[row * 72 + c4] = h;
        }
    }
    __syncthreads();
    short8_t qf[4];
    {
        const int rowl = w * 32 + ql;
#pragma unroll
        for (int tt = 0; tt < 4; ++tt)
            qf[tt] = *(const short8_t*)&smQ[rowl * 72 + tt * 16 + hi * 8];
    }
    __syncthreads();

    // ---- staging: global_load_lds 16B, linear LDS dest, inverse-swizzled src ----
    auto stage = [&](int kt, int buf) {
        const int row = t >> 3, oct = t & 7;
        const int row2 = row + 32;
        {
            const unsigned short* g = KbB + ((size_t)(kt * 64 + row)) * 64 + (oct ^ sw8(row)) * 8;
            __builtin_amdgcn_global_load_lds((const __attribute__((address_space(1))) unsigned int*)g,
                (__attribute__((address_space(3))) unsigned int*)(smK + buf * 4096 + t * 8), 16, 0, 0);
            const unsigned short* g2 = KbB + ((size_t)(kt * 64 + row2)) * 64 + (oct ^ sw8(row2)) * 8;
            __builtin_amdgcn_global_load_lds((const __attribute__((address_space(1))) unsigned int*)g2,
                (__attribute__((address_space(3))) unsigned int*)(smK + buf * 4096 + 2048 + t * 8), 16, 0, 0);
        }
        {
            const unsigned short* g = VtB + (size_t)row * Sn + kt * 64 + (oct ^ sw8(row)) * 8;
            __builtin_amdgcn_global_load_lds((const __attribute__((address_space(1))) unsigned int*)g,
                (__attribute__((address_space(3))) unsigned int*)(smV + buf * 4096 + t * 8), 16, 0, 0);
            const unsigned short* g2 = VtB + (size_t)row2 * Sn + kt * 64 + (oct ^ sw8(row2)) * 8;
            __builtin_amdgcn_global_load_lds((const __attribute__((address_space(1))) unsigned int*)g2,
                (__attribute__((address_space(3))) unsigned int*)(smV + buf * 4096 + 2048 + t * 8), 16, 0, 0);
        }
    };
    auto ldf = [&](const unsigned short* base, int row, int olog) -> short8_t {
        return *(const short8_t*)(base + row * 64 + (olog ^ sw8(row)) * 8);
    };

    f32x16 o0 = zero16(), o1 = zero16();
    float m_run = -INFINITY, l_run = 0.f;
    const int qrow = q0 + w * 32 + ql;
    const unsigned long long* pmrow = PM + ((size_t)b * Sn + qrow) * MW;

    stage(0, 0);
    __syncthreads();

    for (int kt = 0; kt < NKT; ++kt) {
        const int cur = kt & 1;
        if (kt + 1 < NKT) stage(kt + 1, cur ^ 1);
        const unsigned long long bits = pmrow[kt];
        const unsigned short* bK = smK + cur * 4096;
        const unsigned short* bV = smV + cur * 4096;

        // ---- QK^T (swapped): S^T[k][q], lane q = ql, keys in regs ----
        f32x16 s0 = zero16(), s1 = zero16();
        __builtin_amdgcn_s_setprio(1);
#pragma unroll
        for (int tt = 0; tt < 4; ++tt) {
            short8_t a0 = ldf(bK, ql,      2 * tt + hi);
            short8_t a1 = ldf(bK, 32 + ql, 2 * tt + hi);
            s0 = __builtin_amdgcn_mfma_f32_32x32x16_bf16(a0, qf[tt], s0, 0, 0, 0);
            s1 = __builtin_amdgcn_mfma_f32_32x32x16_bf16(a1, qf[tt], s1, 0, 0, 0);
        }
        __builtin_amdgcn_s_setprio(0);

        // ---- mask (reg r holds key = (r&3) + 8*(r>>2) + 4*hi [+32 for s1]) ----
        const unsigned long long bb = bits >> (hi * 4);
        const unsigned blo = (unsigned)bb, bhi = (unsigned)(bb >> 32);
#pragma unroll
        for (int r = 0; r < 16; ++r) {
            const int bp = 8 * (r >> 2) + (r & 3);
            s0[r] = ((blo >> bp) & 1u) ? -1e9f : s0[r];
            s1[r] = ((bhi >> bp) & 1u) ? -1e9f : s1[r];
        }

        // ---- online softmax max (v_max3 chains), lane-local q-row ----
        float mx0 = fmaxf(s0[0], s0[1]);
        float mx1 = fmaxf(s1[0], s1[1]);
#pragma unroll
        for (int r = 2; r < 16; r += 2) {
            mx0 = max3f(mx0, s0[r], s0[r + 1]);
            mx1 = max3f(mx1, s1[r], s1[r + 1]);
        }
        float mx = fmaxf(mx0, mx1);
        mx = fmaxf(mx, __shfl_xor(mx, 32));

        if (!__all(mx - m_run <= 8.0f)) {   // defer-max (THR=8, log2 domain)
            const float mn = fmaxf(m_run, mx);
            const float corr = exp2fast(m_run - mn);
            m_run = mn;
            l_run *= corr;                   // l is lane-local (q = ql)
#pragma unroll
            for (int r = 0; r < 16; ++r) {
                const int qloc = (r & 3) + 8 * (r >> 2) + 4 * hi;
                const float cr = __shfl(corr, qloc);   // lane qloc holds q-row qloc's corr
                o0[r] *= cr; o1[r] *= cr;
            }
        }
#pragma unroll
        for (int r = 0; r < 16; ++r) {
            s0[r] = exp2fast(s0[r] - m_run);
            s1[r] = exp2fast(s1[r] - m_run);
        }

        // ---- l: 4-chain tree sum of the 32 P values, then half-wave combine ----
        {
            float p0 = 0.f, p1 = 0.f, p2 = 0.f, p3 = 0.f;
#pragma unroll
            for (int r = 0; r < 16; r += 4) {
                p0 += s0[r];     p1 += s0[r + 1]; p2 += s0[r + 2]; p3 += s0[r + 3];
                p0 += s1[r];     p1 += s1[r + 1]; p2 += s1[r + 2]; p3 += s1[r + 3];
            }
            float rs = (p0 + p1) + (p2 + p3);
            rs += __shfl_xor(rs, 32);
            l_run += rs;
        }

        // ---- PV: fused cvt+permlane+MFMA per k-slice (low transient regs) ----
        __builtin_amdgcn_s_setprio(1);
#pragma unroll
        for (int ks = 0; ks < 4; ++ks) {
            const f32x16& sv = (ks < 2) ? s0 : s1;
            const int off = (ks & 1) * 8;
            unsigned x0 = cvtpk(sv[off],     sv[off + 1]);
            unsigned x1 = cvtpk(sv[off + 2], sv[off + 3]);
            unsigned y0 = cvtpk(sv[off + 4], sv[off + 5]);
            unsigned y1 = cvtpk(sv[off + 6], sv[off + 7]);
            pswap(x0, y0);   // x0' = frag word0, y0' = frag word2
            pswap(x1, y1);   // x1' = frag word1, y1' = frag word3
            union { unsigned u[4]; short8_t v; } pa;
            pa.u[0] = x0; pa.u[1] = x1; pa.u[2] = y0; pa.u[3] = y1;
            short8_t vf0 = ldf(bV, ql,      2 * ks + hi);
            short8_t vf1 = ldf(bV, 32 + ql, 2 * ks + hi);
            o0 = __builtin_amdgcn_mfma_f32_32x32x16_bf16(pa.v, vf0, o0, 0, 0, 0);
            o1 = __builtin_amdgcn_mfma_f32_32x32x16_bf16(pa.v, vf1, o1, 0, 0, 0);
        }
        __builtin_amdgcn_s_setprio(0);
        __syncthreads();   // drains gload_lds (next tile) + guards buffer reuse
    }

    // ---- epilogue: 1/l redistribution via shfl, store fp32 ----
    const float inv = 1.0f / l_run;
#pragma unroll
    for (int r = 0; r < 16; ++r) {
        const int qloc = (r & 3) + 8 * (r >> 2) + 4 * hi;
        const float iv = __shfl(inv, qloc);
        float* orow = Op + ((size_t)bh * Sn + q0 + w * 32 + qloc) * 64;
        orow[ql] = o0[r] * iv;
        orow[32 + ql] = o1[r] * iv;
    }
}

// ================= fallback (round-2 kernel, proven) =================
__global__ __launch_bounds__(512, 4) void sdpa_v2(
    const float* __restrict__ Qp, const float* __restrict__ Kp,
    const float* __restrict__ Vp, const void* __restrict__ Mp,
    const unsigned long long* __restrict__ PM, float* __restrict__ Op)
{
    __shared__ unsigned short lds_k[64 * 64];
    __shared__ unsigned short lds_vt[64 * 64];
    __shared__ unsigned short lds_p[8][16 * 64];

    const int t = threadIdx.x;
    const int wave = t >> 6;
    const int lane = t & 63;
    const int g = lane >> 4;
    const int c = lane & 15;

    const int gid = blockIdx.x;
    const int lin = (gid & 7) * 128 + (gid >> 3);
    const int bh = lin >> 4;
    const int qb = lin & 15;
    const int b = bh >> 4;
    const int q0 = qb * 128;

    bool m_i32 = true;
    if (!PM) {
        unsigned accv = 0;
        const unsigned* mw = (const unsigned*)Mp;
#pragma unroll
        for (int i = 0; i < 32; ++i) accv |= (mw[i] & 0xFFFFFF00u);
        m_i32 = (accv == 0u);
    }
    const int* mi32 = (const int*)Mp;
    const unsigned char* mu8 = (const unsigned char*)Mp;

    short8_t qf[2];
    {
        const float qscale = 0.125f * 1.44269504088896340736f;
        const float* qsrc = Qp + ((size_t)bh * Sn + q0 + wave * 16 + c) * Dn + g * 8;
#pragma unroll
        for (int h2 = 0; h2 < 2; ++h2) {
            f32x4 f0 = *(const f32x4*)(qsrc + h2 * 32);
            f32x4 f1 = *(const f32x4*)(qsrc + h2 * 32 + 4);
            short8_t v;
            v[0]=(short)f2bf(f0[0]*qscale); v[1]=(short)f2bf(f0[1]*qscale);
            v[2]=(short)f2bf(f0[2]*qscale); v[3]=(short)f2bf(f0[3]*qscale);
            v[4]=(short)f2bf(f1[0]*qscale); v[5]=(short)f2bf(f1[1]*qscale);
            v[6]=(short)f2bf(f1[2]*qscale); v[7]=(short)f2bf(f1[3]*qscale);
            qf[h2] = v;
        }
    }

    f32x4 o[4];
#pragma unroll
    for (int i = 0; i < 4; ++i) o[i] = (f32x4){0.f, 0.f, 0.f, 0.f};
    float m_run[4] = {-INFINITY, -INFINITY, -INFINITY, -INFINITY};
    float l_run[4] = {0.f, 0.f, 0.f, 0.f};

    const float* kbase = Kp + (size_t)bh * Sn * Dn;
    const float* vbase = Vp + (size_t)bh * Sn * Dn;
    const size_t mrow0 = (size_t)b * Sn + q0 + wave * 16 + g * 4;

    for (int kt = 0; kt < NKT; ++kt) {
        const int k0 = kt * 64;
        {
            const int key = t >> 3;
            const int d0 = (t & 7) * 8;
            const float* src = kbase + (size_t)(k0 + key) * Dn + d0;
            f32x4 f0 = *(const f32x4*)src;
            f32x4 f1 = *(const f32x4*)(src + 4);
            short8_t hv;
            hv[0]=(short)f2bf(f0[0]); hv[1]=(short)f2bf(f0[1]);
            hv[2]=(short)f2bf(f0[2]); hv[3]=(short)f2bf(f0[3]);
            hv[4]=(short)f2bf(f1[0]); hv[5]=(short)f2bf(f1[1]);
            hv[6]=(short)f2bf(f1[2]); hv[7]=(short)f2bf(f1[3]);
            *(short8_t*)&lds_k[key * 64 + (d0 ^ (sw8(key) << 3))] = hv;
        }
        {
            const int vv = t & 63;
            const int kq = (t >> 6) * 8;
            short8_t hv;
#pragma unroll
            for (int j = 0; j < 8; ++j)
                hv[j] = (short)f2bf(vbase[(size_t)(k0 + kq + j) * Dn + vv]);
            *(short8_t*)&lds_vt[vv * 64 + (kq ^ (sw8(vv) << 3))] = hv;
        }
        __syncthreads();

        f32x4 s[4];
#pragma unroll
        for (int e = 0; e < 4; ++e) s[e] = (f32x4){0.f, 0.f, 0.f, 0.f};
        __builtin_amdgcn_s_setprio(1);
#pragma unroll
        for (int e = 0; e < 4; ++e) {
            const int ke = e * 16 + c;
            const int swk = sw8(ke) << 3;
            short8_t kf0 = *(const short8_t*)&lds_k[ke * 64 + ((g * 8) ^ swk)];
            short8_t kf1 = *(const short8_t*)&lds_k[ke * 64 + ((32 + g * 8) ^ swk)];
            s[e] = __builtin_amdgcn_mfma_f32_16x16x32_bf16(qf[0], kf0, s[e], 0, 0, 0);
            s[e] = __builtin_amdgcn_mfma_f32_16x16x32_bf16(qf[1], kf1, s[e], 0, 0, 0);
        }
        __builtin_amdgcn_s_setprio(0);

        unsigned long long bits[4];
        if (PM) {
#pragma unroll
            for (int r = 0; r < 4; ++r) bits[r] = PM[(mrow0 + r) * MW + kt];
        } else {
#pragma unroll
            for (int r = 0; r < 4; ++r) {
                const size_t mi = (mrow0 + r) * Sn + k0 + c;
                unsigned long long bbv = 0;
#pragma unroll
                for (int e = 0; e < 4; ++e) {
                    int mm = m_i32 ? mi32[mi + 16 * e] : (int)mu8[mi + 16 * e];
                    bbv |= (unsigned long long)(mm != 0) << (c + 16 * e);
                }
                bits[r] = bbv;
            }
        }

        float p[4][4], mx[4];
#pragma unroll
        for (int r = 0; r < 4; ++r) {
            const unsigned lo = (unsigned)bits[r];
            const unsigned hh = (unsigned)(bits[r] >> 32);
            const unsigned t0 = lo >> c;
            const unsigned t1 = hh >> c;
            float v0 = (t0 & 1u)       ? -1e9f : s[0][r];
            float v1 = (t0 & 0x10000u) ? -1e9f : s[1][r];
            float v2 = (t1 & 1u)       ? -1e9f : s[2][r];
            float v3 = (t1 & 0x10000u) ? -1e9f : s[3][r];
            p[0][r] = v0; p[1][r] = v1; p[2][r] = v2; p[3][r] = v3;
            mx[r] = fmaxf(fmaxf(v0, v1), fmaxf(v2, v3));
        }
#pragma unroll
        for (int sh = 1; sh < 16; sh <<= 1) {
#pragma unroll
            for (int r = 0; r < 4; ++r) mx[r] = fmaxf(mx[r], __shfl_xor(mx[r], sh));
        }
        float need = mx[0] - m_run[0];
        need = fmaxf(need, mx[1] - m_run[1]);
        need = fmaxf(need, mx[2] - m_run[2]);
        need = fmaxf(need, mx[3] - m_run[3]);
        if (!__all(need <= 8.0f)) {
#pragma unroll
            for (int r = 0; r < 4; ++r) {
                const float mn = fmaxf(m_run[r], mx[r]);
                const float corr = exp2fast(m_run[r] - mn);
                m_run[r] = mn;
                l_run[r] *= corr;
#pragma unroll
                for (int cg = 0; cg < 4; ++cg) o[cg][r] *= corr;
            }
        }
        float rsv[4];
#pragma unroll
        for (int r = 0; r < 4; ++r) {
            p[0][r] = exp2fast(p[0][r] - m_run[r]);
            p[1][r] = exp2fast(p[1][r] - m_run[r]);
            p[2][r] = exp2fast(p[2][r] - m_run[r]);
            p[3][r] = exp2fast(p[3][r] - m_run[r]);
            rsv[r] = (p[0][r] + p[1][r]) + (p[2][r] + p[3][r]);
        }
#pragma unroll
        for (int sh = 1; sh < 16; sh <<= 1) {
#pragma unroll
            for (int r = 0; r < 4; ++r) rsv[r] += __shfl_xor(rsv[r], sh);
        }
#pragma unroll
        for (int r = 0; r < 4; ++r) l_run[r] += rsv[r];

        unsigned short* pw = lds_p[wave];
#pragma unroll
        for (int r = 0; r < 4; ++r) {
            const int row = g * 4 + r;
            const int swp = sw8(row) << 3;
            pw[row * 64 + ((c)      ^ swp)] = f2bf(p[0][r]);
            pw[row * 64 + ((c + 16) ^ swp)] = f2bf(p[1][r]);
            pw[row * 64 + ((c + 32) ^ swp)] = f2bf(p[2][r]);
            pw[row * 64 + ((c + 48) ^ swp)] = f2bf(p[3][r]);
        }
        const int swc = sw8(c) << 3;
        const short8_t pf0 = *(const short8_t*)&pw[c * 64 + ((g * 8) ^ swc)];
        const short8_t pf1 = *(const short8_t*)&pw[c * 64 + ((32 + g * 8) ^ swc)];
        __builtin_amdgcn_s_setprio(1);
#pragma unroll
        for (int cg = 0; cg < 4; ++cg) {
            const int vv = cg * 16 + c;
            const int swv = sw8(vv) << 3;
            const short8_t vf0 = *(const short8_t*)&lds_vt[vv * 64 + ((g * 8) ^ swv)];
            const short8_t vf1 = *(const short8_t*)&lds_vt[vv * 64 + ((32 + g * 8) ^ swv)];
            o[cg] = __builtin_amdgcn_mfma_f32_16x16x32_bf16(pf0, vf0, o[cg], 0, 0, 0);
            o[cg] = __builtin_amdgcn_mfma_f32_16x16x32_bf16(pf1, vf1, o[cg], 0, 0, 0);
        }
        __builtin_amdgcn_s_setprio(0);
        __syncthreads();
    }

#pragma unroll
    for (int r = 0; r < 4; ++r) {
        const float inv = 1.0f / l_run[r];
        float* orow = Op + ((size_t)bh * Sn + q0 + wave * 16 + g * 4 + r) * Dn + c;
#pragma unroll
        for (int cg = 0; cg < 4; ++cg) orow[cg * 16] = o[cg][r] * inv;
    }
}

extern "C" void kernel_launch(void* const* d_in, const int* in_sizes, int n_in,
                              void* d_out, int out_size, void* d_ws, size_t ws_size,
                              hipStream_t stream) {
    (void)in_sizes; (void)n_in; (void)out_size;
    const float* Q = (const float*)d_in[0];
    const float* K = (const float*)d_in[1];
    const float* V = (const float*)d_in[2];
    const void*  M = d_in[3];
    float* O = (float*)d_out;

    const size_t pmB = (size_t)Bn * Sn * MW * 8;            // 2 MB packed mask
    const size_t kvB = (size_t)Bn * Hn * Sn * Dn * 2;       // 16.78 MB each

    if (ws_size >= pmB + 2 * kvB) {
        unsigned long long* PM = (unsigned long long*)d_ws;
        unsigned short* Kb = (unsigned short*)((char*)d_ws + pmB);
        unsigned short* Vt = (unsigned short*)((char*)d_ws + pmB + kvB);
        pack_mask<<<1024, 256, 0, stream>>>(M, PM);
        convK<<<4096, 256, 0, stream>>>(K, Kb);
        convV<<<dim3(Bn * Hn, NKT), 256, 0, stream>>>(V, Vt);
        sdpa_v3<<<dim3(1024), dim3(256), 0, stream>>>(Q, Kb, Vt, PM, O);
    } else {
        unsigned long long* PM = nullptr;
        if (ws_size >= pmB) {
            PM = (unsigned long long*)d_ws;
            pack_mask<<<1024, 256, 0, stream>>>(M, PM);
        }
        sdpa_v2<<<dim3(1024), dim3(512), 0, stream>>>(Q, K, V, M, PM, O);
    }
}

// Round 8
// 145.130 us; speedup vs baseline: 2.6928x; 1.0097x over previous
//
#include <hip/hip_runtime.h>
#include <hip/hip_bf16.h>
#include <math.h>

typedef __attribute__((ext_vector_type(4)))  float f32x4;
typedef __attribute__((ext_vector_type(16))) float f32x16;
typedef __attribute__((ext_vector_type(8)))  short short8_t;
typedef __attribute__((ext_vector_type(4)))  short short4_t;

constexpr int Bn = 4, Hn = 16, Sn = 2048, Dn = 64;
constexpr int MW  = Sn / 64;   // packed-mask u64 words per row = 32
constexpr int NKT = Sn / 64;   // 64-key tiles = 32

__device__ __forceinline__ unsigned short f2bf(float f) {
    union { float f; unsigned u; } x; x.f = f;
    unsigned r = x.u + 0x7fffu + ((x.u >> 16) & 1u);  // RTNE
    return (unsigned short)(r >> 16);
}
__device__ __forceinline__ int sw8(int row) { return (row ^ (row >> 3)) & 7; }
__device__ __forceinline__ float exp2fast(float x) {
#if __has_builtin(__builtin_amdgcn_exp2f)
    return __builtin_amdgcn_exp2f(x);
#else
    float r; asm("v_exp_f32 %0, %1" : "=v"(r) : "v"(x)); return r;
#endif
}
__device__ __forceinline__ float max3f(float a, float b, float c) {
    return fmaxf(fmaxf(a, b), c);   // fuses to v_max3_f32
}
__device__ __forceinline__ f32x16 zero16() {
    f32x16 z;
#pragma unroll
    for (int i = 0; i < 16; ++i) z[i] = 0.f;
    return z;
}
__device__ __forceinline__ unsigned cvtpk(float lo, float hi_) {
    __hip_bfloat162 h2 = __float22bfloat162_rn(make_float2(lo, hi_));
    union { __hip_bfloat162 h; unsigned u; } u; u.h = h2;
    return u.u;
}
// v_permlane32_swap_b32: X' = [X_lo, Y_lo], Y' = [X_hi, Y_hi]
__device__ __forceinline__ void pswap(unsigned &x, unsigned &y) {
    asm("v_permlane32_swap_b32 %0, %1" : "+v"(x), "+v"(y));
}

// ================= prepass kernels =================
__global__ __launch_bounds__(256) void pack_mask(const void* __restrict__ Mp,
                                                 unsigned long long* __restrict__ PM) {
    unsigned accv = 0;
    {
        const unsigned* mw = (const unsigned*)Mp;
#pragma unroll
        for (int i = 0; i < 8; ++i) accv |= (mw[i] & 0xFFFFFF00u);
    }
    const bool i32 = (accv == 0u);
    const int lane = threadIdx.x & 63;
    const int wv = (int)((blockIdx.x * 256 + threadIdx.x) >> 6);   // 4096 waves
    const int w0 = wv * (Bn * Sn * MW / 4096);                     // 64 words/wave
    const int* mi32 = (const int*)Mp;
    const unsigned char* mu8 = (const unsigned char*)Mp;
    for (int j = 0; j < 64; j += 4) {
        int m0, m1, m2, m3;
        if (i32) {
            m0 = mi32[(size_t)(w0 + j) * 64 + lane];
            m1 = mi32[(size_t)(w0 + j + 1) * 64 + lane];
            m2 = mi32[(size_t)(w0 + j + 2) * 64 + lane];
            m3 = mi32[(size_t)(w0 + j + 3) * 64 + lane];
        } else {
            m0 = mu8[(size_t)(w0 + j) * 64 + lane];
            m1 = mu8[(size_t)(w0 + j + 1) * 64 + lane];
            m2 = mu8[(size_t)(w0 + j + 2) * 64 + lane];
            m3 = mu8[(size_t)(w0 + j + 3) * 64 + lane];
        }
        unsigned long long b0 = __ballot(m0 != 0);
        unsigned long long b1 = __ballot(m1 != 0);
        unsigned long long b2 = __ballot(m2 != 0);
        unsigned long long b3 = __ballot(m3 != 0);
        if (lane == 0) {
            PM[w0 + j] = b0; PM[w0 + j + 1] = b1;
            PM[w0 + j + 2] = b2; PM[w0 + j + 3] = b3;
        }
    }
}

// fused K->bf16 (linear) + V->bf16 transposed, one block per (bh, kt)
__global__ __launch_bounds__(256) void convKV(const float* __restrict__ K,
                                              const float* __restrict__ V,
                                              unsigned short* __restrict__ Kb,
                                              unsigned short* __restrict__ Vt) {
    __shared__ unsigned short tile[64 * 72];
    const int bh = blockIdx.x, kt = blockIdx.y, t = threadIdx.x;

    // ---- K: 64 rows x 64 d, straight bf16 convert ----
    {
        const float* ksrc = K + ((size_t)bh * Sn + kt * 64) * 64;
        unsigned short* kdst = Kb + ((size_t)bh * Sn + kt * 64) * 64;
#pragma unroll
        for (int j = 0; j < 2; ++j) {
            const int idx = j * 256 + t;       // 512 chunks of 8 floats
            f32x4 a = *(const f32x4*)(ksrc + idx * 8);
            f32x4 b = *(const f32x4*)(ksrc + idx * 8 + 4);
            short8_t h;
            h[0]=(short)f2bf(a[0]); h[1]=(short)f2bf(a[1]); h[2]=(short)f2bf(a[2]); h[3]=(short)f2bf(a[3]);
            h[4]=(short)f2bf(b[0]); h[5]=(short)f2bf(b[1]); h[6]=(short)f2bf(b[2]); h[7]=(short)f2bf(b[3]);
            *(short8_t*)(kdst + idx * 8) = h;
        }
    }

    // ---- V: transpose via LDS -> Vt[bh][v][k] ----
    {
        const int k = t >> 2, vq = (t & 3) * 16;
        const float* src = V + ((size_t)bh * Sn + kt * 64 + k) * 64 + vq;
#pragma unroll
        for (int j = 0; j < 4; ++j) {
            f32x4 f = *(const f32x4*)(src + j * 4);
            short4_t h;
            h[0]=(short)f2bf(f[0]); h[1]=(short)f2bf(f[1]); h[2]=(short)f2bf(f[2]); h[3]=(short)f2bf(f[3]);
            *(short4_t*)&tile[k * 72 + vq + j * 4] = h;
        }
        __syncthreads();
#pragma unroll
        for (int j = 0; j < 2; ++j) {
            const int v = (t >> 3) + 32 * j;
            const int oct = t & 7;
            short8_t h;
#pragma unroll
            for (int i2 = 0; i2 < 8; ++i2) h[i2] = (short)tile[(oct * 8 + i2) * 72 + v];
            *(short8_t*)(Vt + ((size_t)bh * 64 + v) * Sn + kt * 64 + oct * 8) = h;
        }
    }
}

// ====== main kernel (round-6 proven version): swapped-QK^T, permlane PV, online max ======
__global__ __launch_bounds__(256, 3) void sdpa_v3(
    const float* __restrict__ Qp, const unsigned short* __restrict__ Kb,
    const unsigned short* __restrict__ Vt, const unsigned long long* __restrict__ PM,
    float* __restrict__ Op)
{
    __shared__ __align__(16) char smem[32768];
    unsigned short* smK = (unsigned short*)smem;            // [2][4096]
    unsigned short* smV = (unsigned short*)(smem + 16384);  // [2][4096]
    unsigned short* smQ = (unsigned short*)smem;            // prologue overlay [128][72]

    const int t = threadIdx.x;
    const int w = t >> 6;
    const int l = t & 63;
    const int ql = l & 31;
    const int hi = l >> 5;

    // XCD-aware remap (1024 blocks = 8 XCD * 128)
    const int gid = blockIdx.x;
    const int lin = (gid & 7) * 128 + (gid >> 3);
    const int bh = lin >> 4;
    const int qb = lin & 15;
    const int b = bh >> 4;
    const int q0 = qb * 128;

    const unsigned short* KbB = Kb + (size_t)bh * Sn * 64;
    const unsigned short* VtB = Vt + (size_t)bh * 64 * Sn;

    // ---- prologue: cooperative Q load -> smQ (bf16, scaled), then frags ----
    {
        const float qscale = 0.125f * 1.44269504088896340736f;  // 1/sqrt(64) * log2(e)
        const float* Qbase = Qp + ((size_t)bh * Sn + q0) * Dn;
#pragma unroll
        for (int j = 0; j < 8; ++j) {
            const int flat = j * 256 + t;           // 2048 f32x4 chunks
            const int row = flat >> 4, c4 = (flat & 15) * 4;
            f32x4 f = *(const f32x4*)(Qbase + (size_t)flat * 4);
            short4_t h;
            h[0]=(short)f2bf(f[0]*qscale); h[1]=(short)f2bf(f[1]*qscale);
            h[2]=(short)f2bf(f[2]*qscale); h[3]=(short)f2bf(f[3]*qscale);
            *(short4_t*)&smQ[row * 72 + c4] = h;
        }
    }
    __syncthreads();
    short8_t qf[4];
    {
        const int rowl = w * 32 + ql;
#pragma unroll
        for (int tt = 0; tt < 4; ++tt)
            qf[tt] = *(const short8_t*)&smQ[rowl * 72 + tt * 16 + hi * 8];
    }
    __syncthreads();

    // ---- staging: global_load_lds 16B, linear LDS dest, inverse-swizzled src ----
    auto stage = [&](int kt, int buf) {
        const int row = t >> 3, oct = t & 7;
        const int row2 = row + 32;
        {
            const unsigned short* g = KbB + ((size_t)(kt * 64 + row)) * 64 + (oct ^ sw8(row)) * 8;
            __builtin_amdgcn_global_load_lds((const __attribute__((address_space(1))) unsigned int*)g,
                (__attribute__((address_space(3))) unsigned int*)(smK + buf * 4096 + t * 8), 16, 0, 0);
            const unsigned short* g2 = KbB + ((size_t)(kt * 64 + row2)) * 64 + (oct ^ sw8(row2)) * 8;
            __builtin_amdgcn_global_load_lds((const __attribute__((address_space(1))) unsigned int*)g2,
                (__attribute__((address_space(3))) unsigned int*)(smK + buf * 4096 + 2048 + t * 8), 16, 0, 0);
        }
        {
            const unsigned short* g = VtB + (size_t)row * Sn + kt * 64 + (oct ^ sw8(row)) * 8;
            __builtin_amdgcn_global_load_lds((const __attribute__((address_space(1))) unsigned int*)g,
                (__attribute__((address_space(3))) unsigned int*)(smV + buf * 4096 + t * 8), 16, 0, 0);
            const unsigned short* g2 = VtB + (size_t)row2 * Sn + kt * 64 + (oct ^ sw8(row2)) * 8;
            __builtin_amdgcn_global_load_lds((const __attribute__((address_space(1))) unsigned int*)g2,
                (__attribute__((address_space(3))) unsigned int*)(smV + buf * 4096 + 2048 + t * 8), 16, 0, 0);
        }
    };
    auto ldf = [&](const unsigned short* base, int row, int olog) -> short8_t {
        return *(const short8_t*)(base + row * 64 + (olog ^ sw8(row)) * 8);
    };

    f32x16 o0 = zero16(), o1 = zero16();
    float m_run = -INFINITY, l_run = 0.f;
    const int qrow = q0 + w * 32 + ql;
    const unsigned long long* pmrow = PM + ((size_t)b * Sn + qrow) * MW;

    stage(0, 0);
    __syncthreads();

    for (int kt = 0; kt < NKT; ++kt) {
        const int cur = kt & 1;
        if (kt + 1 < NKT) stage(kt + 1, cur ^ 1);
        const unsigned long long bits = pmrow[kt];
        const unsigned short* bK = smK + cur * 4096;
        const unsigned short* bV = smV + cur * 4096;

        // ---- QK^T (swapped): S^T[k][q], lane q = ql, keys in regs ----
        f32x16 s0 = zero16(), s1 = zero16();
        __builtin_amdgcn_s_setprio(1);
#pragma unroll
        for (int tt = 0; tt < 4; ++tt) {
            short8_t a0 = ldf(bK, ql,      2 * tt + hi);
            short8_t a1 = ldf(bK, 32 + ql, 2 * tt + hi);
            s0 = __builtin_amdgcn_mfma_f32_32x32x16_bf16(a0, qf[tt], s0, 0, 0, 0);
            s1 = __builtin_amdgcn_mfma_f32_32x32x16_bf16(a1, qf[tt], s1, 0, 0, 0);
        }
        __builtin_amdgcn_s_setprio(0);

        // ---- mask (reg r holds key = (r&3) + 8*(r>>2) + 4*hi [+32 for s1]) ----
        const unsigned long long bb = bits >> (hi * 4);
        const unsigned blo = (unsigned)bb, bhi = (unsigned)(bb >> 32);
#pragma unroll
        for (int r = 0; r < 16; ++r) {
            const int bp = 8 * (r >> 2) + (r & 3);
            s0[r] = ((blo >> bp) & 1u) ? -1e9f : s0[r];
            s1[r] = ((bhi >> bp) & 1u) ? -1e9f : s1[r];
        }

        // ---- online softmax max (v_max3 chains), lane-local q-row ----
        float mx0 = fmaxf(s0[0], s0[1]);
        float mx1 = fmaxf(s1[0], s1[1]);
#pragma unroll
        for (int r = 2; r < 16; r += 2) {
            mx0 = max3f(mx0, s0[r], s0[r + 1]);
            mx1 = max3f(mx1, s1[r], s1[r + 1]);
        }
        float mx = fmaxf(mx0, mx1);
        mx = fmaxf(mx, __shfl_xor(mx, 32));

        if (!__all(mx - m_run <= 8.0f)) {   // defer-max (THR=8, log2 domain)
            const float mn = fmaxf(m_run, mx);
            const float corr = exp2fast(m_run - mn);
            m_run = mn;
            l_run *= corr;                   // l is lane-local (q = ql)
#pragma unroll
            for (int r = 0; r < 16; ++r) {
                const int qloc = (r & 3) + 8 * (r >> 2) + 4 * hi;
                const float cr = __shfl(corr, qloc);   // lane qloc holds q-row qloc's corr
                o0[r] *= cr; o1[r] *= cr;
            }
        }
#pragma unroll
        for (int r = 0; r < 16; ++r) {
            s0[r] = exp2fast(s0[r] - m_run);
            s1[r] = exp2fast(s1[r] - m_run);
        }

        // ---- l: 4-chain tree sum of the 32 P values, then half-wave combine ----
        {
            float p0 = 0.f, p1 = 0.f, p2 = 0.f, p3 = 0.f;
#pragma unroll
            for (int r = 0; r < 16; r += 4) {
                p0 += s0[r];     p1 += s0[r + 1]; p2 += s0[r + 2]; p3 += s0[r + 3];
                p0 += s1[r];     p1 += s1[r + 1]; p2 += s1[r + 2]; p3 += s1[r + 3];
            }
            float rs = (p0 + p1) + (p2 + p3);
            rs += __shfl_xor(rs, 32);
            l_run += rs;
        }

        // ---- PV: fused cvt+permlane+MFMA per k-slice (low transient regs) ----
        __builtin_amdgcn_s_setprio(1);
#pragma unroll
        for (int ks = 0; ks < 4; ++ks) {
            const f32x16& sv = (ks < 2) ? s0 : s1;
            const int off = (ks & 1) * 8;
            unsigned x0 = cvtpk(sv[off],     sv[off + 1]);
            unsigned x1 = cvtpk(sv[off + 2], sv[off + 3]);
            unsigned y0 = cvtpk(sv[off + 4], sv[off + 5]);
            unsigned y1 = cvtpk(sv[off + 6], sv[off + 7]);
            pswap(x0, y0);   // x0' = frag word0, y0' = frag word2
            pswap(x1, y1);   // x1' = frag word1, y1' = frag word3
            union { unsigned u[4]; short8_t v; } pa;
            pa.u[0] = x0; pa.u[1] = x1; pa.u[2] = y0; pa.u[3] = y1;
            short8_t vf0 = ldf(bV, ql,      2 * ks + hi);
            short8_t vf1 = ldf(bV, 32 + ql, 2 * ks + hi);
            o0 = __builtin_amdgcn_mfma_f32_32x32x16_bf16(pa.v, vf0, o0, 0, 0, 0);
            o1 = __builtin_amdgcn_mfma_f32_32x32x16_bf16(pa.v, vf1, o1, 0, 0, 0);
        }
        __builtin_amdgcn_s_setprio(0);
        __syncthreads();   // drains gload_lds (next tile) + guards buffer reuse
    }

    // ---- epilogue: 1/l redistribution via shfl, store fp32 ----
    const float inv = 1.0f / l_run;
#pragma unroll
    for (int r = 0; r < 16; ++r) {
        const int qloc = (r & 3) + 8 * (r >> 2) + 4 * hi;
        const float iv = __shfl(inv, qloc);
        float* orow = Op + ((size_t)bh * Sn + q0 + w * 32 + qloc) * 64;
        orow[ql] = o0[r] * iv;
        orow[32 + ql] = o1[r] * iv;
    }
}

// ================= fallback (round-2 kernel, proven) =================
__global__ __launch_bounds__(512, 4) void sdpa_v2(
    const float* __restrict__ Qp, const float* __restrict__ Kp,
    const float* __restrict__ Vp, const void* __restrict__ Mp,
    const unsigned long long* __restrict__ PM, float* __restrict__ Op)
{
    __shared__ unsigned short lds_k[64 * 64];
    __shared__ unsigned short lds_vt[64 * 64];
    __shared__ unsigned short lds_p[8][16 * 64];

    const int t = threadIdx.x;
    const int wave = t >> 6;
    const int lane = t & 63;
    const int g = lane >> 4;
    const int c = lane & 15;

    const int gid = blockIdx.x;
    const int lin = (gid & 7) * 128 + (gid >> 3);
    const int bh = lin >> 4;
    const int qb = lin & 15;
    const int b = bh >> 4;
    const int q0 = qb * 128;

    bool m_i32 = true;
    if (!PM) {
        unsigned accv = 0;
        const unsigned* mw = (const unsigned*)Mp;
#pragma unroll
        for (int i = 0; i < 32; ++i) accv |= (mw[i] & 0xFFFFFF00u);
        m_i32 = (accv == 0u);
    }
    const int* mi32 = (const int*)Mp;
    const unsigned char* mu8 = (const unsigned char*)Mp;

    short8_t qf[2];
    {
        const float qscale = 0.125f * 1.44269504088896340736f;
        const float* qsrc = Qp + ((size_t)bh * Sn + q0 + wave * 16 + c) * Dn + g * 8;
#pragma unroll
        for (int h2 = 0; h2 < 2; ++h2) {
            f32x4 f0 = *(const f32x4*)(qsrc + h2 * 32);
            f32x4 f1 = *(const f32x4*)(qsrc + h2 * 32 + 4);
            short8_t v;
            v[0]=(short)f2bf(f0[0]*qscale); v[1]=(short)f2bf(f0[1]*qscale);
            v[2]=(short)f2bf(f0[2]*qscale); v[3]=(short)f2bf(f0[3]*qscale);
            v[4]=(short)f2bf(f1[0]*qscale); v[5]=(short)f2bf(f1[1]*qscale);
            v[6]=(short)f2bf(f1[2]*qscale); v[7]=(short)f2bf(f1[3]*qscale);
            qf[h2] = v;
        }
    }

    f32x4 o[4];
#pragma unroll
    for (int i = 0; i < 4; ++i) o[i] = (f32x4){0.f, 0.f, 0.f, 0.f};
    float m_run[4] = {-INFINITY, -INFINITY, -INFINITY, -INFINITY};
    float l_run[4] = {0.f, 0.f, 0.f, 0.f};

    const float* kbase = Kp + (size_t)bh * Sn * Dn;
    const float* vbase = Vp + (size_t)bh * Sn * Dn;
    const size_t mrow0 = (size_t)b * Sn + q0 + wave * 16 + g * 4;

    for (int kt = 0; kt < NKT; ++kt) {
        const int k0 = kt * 64;
        {
            const int key = t >> 3;
            const int d0 = (t & 7) * 8;
            const float* src = kbase + (size_t)(k0 + key) * Dn + d0;
            f32x4 f0 = *(const f32x4*)src;
            f32x4 f1 = *(const f32x4*)(src + 4);
            short8_t hv;
            hv[0]=(short)f2bf(f0[0]); hv[1]=(short)f2bf(f0[1]);
            hv[2]=(short)f2bf(f0[2]); hv[3]=(short)f2bf(f0[3]);
            hv[4]=(short)f2bf(f1[0]); hv[5]=(short)f2bf(f1[1]);
            hv[6]=(short)f2bf(f1[2]); hv[7]=(short)f2bf(f1[3]);
            *(short8_t*)&lds_k[key * 64 + (d0 ^ (sw8(key) << 3))] = hv;
        }
        {
            const int vv = t & 63;
            const int kq = (t >> 6) * 8;
            short8_t hv;
#pragma unroll
            for (int j = 0; j < 8; ++j)
                hv[j] = (short)f2bf(vbase[(size_t)(k0 + kq + j) * Dn + vv]);
            *(short8_t*)&lds_vt[vv * 64 + (kq ^ (sw8(vv) << 3))] = hv;
        }
        __syncthreads();

        f32x4 s[4];
#pragma unroll
        for (int e = 0; e < 4; ++e) s[e] = (f32x4){0.f, 0.f, 0.f, 0.f};
        __builtin_amdgcn_s_setprio(1);
#pragma unroll
        for (int e = 0; e < 4; ++e) {
            const int ke = e * 16 + c;
            const int swk = sw8(ke) << 3;
            short8_t kf0 = *(const short8_t*)&lds_k[ke * 64 + ((g * 8) ^ swk)];
            short8_t kf1 = *(const short8_t*)&lds_k[ke * 64 + ((32 + g * 8) ^ swk)];
            s[e] = __builtin_amdgcn_mfma_f32_16x16x32_bf16(qf[0], kf0, s[e], 0, 0, 0);
            s[e] = __builtin_amdgcn_mfma_f32_16x16x32_bf16(qf[1], kf1, s[e], 0, 0, 0);
        }
        __builtin_amdgcn_s_setprio(0);

        unsigned long long bits[4];
        if (PM) {
#pragma unroll
            for (int r = 0; r < 4; ++r) bits[r] = PM[(mrow0 + r) * MW + kt];
        } else {
#pragma unroll
            for (int r = 0; r < 4; ++r) {
                const size_t mi = (mrow0 + r) * Sn + k0 + c;
                unsigned long long bbv = 0;
#pragma unroll
                for (int e = 0; e < 4; ++e) {
                    int mm = m_i32 ? mi32[mi + 16 * e] : (int)mu8[mi + 16 * e];
                    bbv |= (unsigned long long)(mm != 0) << (c + 16 * e);
                }
                bits[r] = bbv;
            }
        }

        float p[4][4], mx[4];
#pragma unroll
        for (int r = 0; r < 4; ++r) {
            const unsigned lo = (unsigned)bits[r];
            const unsigned hh = (unsigned)(bits[r] >> 32);
            const unsigned t0 = lo >> c;
            const unsigned t1 = hh >> c;
            float v0 = (t0 & 1u)       ? -1e9f : s[0][r];
            float v1 = (t0 & 0x10000u) ? -1e9f : s[1][r];
            float v2 = (t1 & 1u)       ? -1e9f : s[2][r];
            float v3 = (t1 & 0x10000u) ? -1e9f : s[3][r];
            p[0][r] = v0; p[1][r] = v1; p[2][r] = v2; p[3][r] = v3;
            mx[r] = fmaxf(fmaxf(v0, v1), fmaxf(v2, v3));
        }
#pragma unroll
        for (int sh = 1; sh < 16; sh <<= 1) {
#pragma unroll
            for (int r = 0; r < 4; ++r) mx[r] = fmaxf(mx[r], __shfl_xor(mx[r], sh));
        }
        float need = mx[0] - m_run[0];
        need = fmaxf(need, mx[1] - m_run[1]);
        need = fmaxf(need, mx[2] - m_run[2]);
        need = fmaxf(need, mx[3] - m_run[3]);
        if (!__all(need <= 8.0f)) {
#pragma unroll
            for (int r = 0; r < 4; ++r) {
                const float mn = fmaxf(m_run[r], mx[r]);
                const float corr = exp2fast(m_run[r] - mn);
                m_run[r] = mn;
                l_run[r] *= corr;
#pragma unroll
                for (int cg = 0; cg < 4; ++cg) o[cg][r] *= corr;
            }
        }
        float rsv[4];
#pragma unroll
        for (int r = 0; r < 4; ++r) {
            p[0][r] = exp2fast(p[0][r] - m_run[r]);
            p[1][r] = exp2fast(p[1][r] - m_run[r]);
            p[2][r] = exp2fast(p[2][r] - m_run[r]);
            p[3][r] = exp2fast(p[3][r] - m_run[r]);
            rsv[r] = (p[0][r] + p[1][r]) + (p[2][r] + p[3][r]);
        }
#pragma unroll
        for (int sh = 1; sh < 16; sh <<= 1) {
#pragma unroll
            for (int r = 0; r < 4; ++r) rsv[r] += __shfl_xor(rsv[r], sh);
        }
#pragma unroll
        for (int r = 0; r < 4; ++r) l_run[r] += rsv[r];

        unsigned short* pw = lds_p[wave];
#pragma unroll
        for (int r = 0; r < 4; ++r) {
            const int row = g * 4 + r;
            const int swp = sw8(row) << 3;
            pw[row * 64 + ((c)      ^ swp)] = f2bf(p[0][r]);
            pw[row * 64 + ((c + 16) ^ swp)] = f2bf(p[1][r]);
            pw[row * 64 + ((c + 32) ^ swp)] = f2bf(p[2][r]);
            pw[row * 64 + ((c + 48) ^ swp)] = f2bf(p[3][r]);
        }
        const int swc = sw8(c) << 3;
        const short8_t pf0 = *(const short8_t*)&pw[c * 64 + ((g * 8) ^ swc)];
        const short8_t pf1 = *(const short8_t*)&pw[c * 64 + ((32 + g * 8) ^ swc)];
        __builtin_amdgcn_s_setprio(1);
#pragma unroll
        for (int cg = 0; cg < 4; ++cg) {
            const int vv = cg * 16 + c;
            const int swv = sw8(vv) << 3;
            const short8_t vf0 = *(const short8_t*)&lds_vt[vv * 64 + ((g * 8) ^ swv)];
            const short8_t vf1 = *(const short8_t*)&lds_vt[vv * 64 + ((32 + g * 8) ^ swv)];
            o[cg] = __builtin_amdgcn_mfma_f32_16x16x32_bf16(pf0, vf0, o[cg], 0, 0, 0);
            o[cg] = __builtin_amdgcn_mfma_f32_16x16x32_bf16(pf1, vf1, o[cg], 0, 0, 0);
        }
        __builtin_amdgcn_s_setprio(0);
        __syncthreads();
    }

#pragma unroll
    for (int r = 0; r < 4; ++r) {
        const float inv = 1.0f / l_run[r];
        float* orow = Op + ((size_t)bh * Sn + q0 + wave * 16 + g * 4 + r) * Dn + c;
#pragma unroll
        for (int cg = 0; cg < 4; ++cg) orow[cg * 16] = o[cg][r] * inv;
    }
}

extern "C" void kernel_launch(void* const* d_in, const int* in_sizes, int n_in,
                              void* d_out, int out_size, void* d_ws, size_t ws_size,
                              hipStream_t stream) {
    (void)in_sizes; (void)n_in; (void)out_size;
    const float* Q = (const float*)d_in[0];
    const float* K = (const float*)d_in[1];
    const float* V = (const float*)d_in[2];
    const void*  M = d_in[3];
    float* O = (float*)d_out;

    const size_t pmB = (size_t)Bn * Sn * MW * 8;            // 2 MB packed mask
    const size_t kvB = (size_t)Bn * Hn * Sn * Dn * 2;       // 16.78 MB each

    if (ws_size >= pmB + 2 * kvB) {
        unsigned long long* PM = (unsigned long long*)d_ws;
        unsigned short* Kb = (unsigned short*)((char*)d_ws + pmB);
        unsigned short* Vt = (unsigned short*)((char*)d_ws + pmB + kvB);
        pack_mask<<<1024, 256, 0, stream>>>(M, PM);
        convKV<<<dim3(Bn * Hn, NKT), 256, 0, stream>>>(K, V, Kb, Vt);
        sdpa_v3<<<dim3(1024), dim3(256), 0, stream>>>(Q, Kb, Vt, PM, O);
    } else {
        unsigned long long* PM = nullptr;
        if (ws_size >= pmB) {
            PM = (unsigned long long*)d_ws;
            pack_mask<<<1024, 256, 0, stream>>>(M, PM);
        }
        sdpa_v2<<<dim3(1024), dim3(512), 0, stream>>>(Q, K, V, M, PM, O);
    }
}